// Round 3
// baseline (442.071 us; speedup 1.0000x reference)
//
#include <hip/hip_runtime.h>
#include <hip/hip_bf16.h>
#include <stdint.h>

#define S_LEN 2048
#define HIDDEN 3584
#define NH 28
#define NKH 4
#define DH 128
#define NG 7          // NH / NKH
#define NQKV 4608     // (NH + 2*NKH) * DH
#define QD 3584       // NH*DH
#define KD 512        // NKH*DH

using bf16x8 = __attribute__((ext_vector_type(8))) __bf16;
using f32x4  = __attribute__((ext_vector_type(4))) float;
using f32x16 = __attribute__((ext_vector_type(16))) float;

#define AS3(p) ((__attribute__((address_space(3))) void*)(p))
#define AS1(p) ((const __attribute__((address_space(1))) void*)(p))

__device__ __forceinline__ unsigned short f2bf(float f) {
    unsigned u = __float_as_uint(f);
    u += 0x7FFFu + ((u >> 16) & 1u);
    return (unsigned short)(u >> 16);
}
__device__ __forceinline__ unsigned pkbf(float a, float b) {
    return (unsigned)f2bf(a) | ((unsigned)f2bf(b) << 16);
}
__device__ __forceinline__ float bflo(unsigned u) { return __uint_as_float(u << 16); }
__device__ __forceinline__ float bfhi(unsigned u) { return __uint_as_float(u & 0xffff0000u); }

// ---------------- f32 -> bf16 convert (vectorized) ----------------
__global__ void cvt_f32_bf16(const float* __restrict__ in,
                             unsigned short* __restrict__ out, int n4) {
    int i = blockIdx.x * blockDim.x + threadIdx.x;
    if (i >= n4) return;
    float4 v = ((const float4*)in)[i];
    ushort4 o;
    o.x = f2bf(v.x); o.y = f2bf(v.y); o.z = f2bf(v.z); o.w = f2bf(v.w);
    ((ushort4*)out)[i] = o;
}

// ---------------- bf16 GEMM: C[M][N] = A[M][K] * B[N][K]^T (+bias) ----------------
__global__ __launch_bounds__(256) void gemm_bf16(
    const unsigned short* __restrict__ A,
    const unsigned short* __restrict__ B,
    float* __restrict__ C,
    const float* __restrict__ bias,
    int M, int N, int K)
{
    __shared__ __align__(16) unsigned char smem[32768];
    unsigned char* As = smem;           // 128 rows x 128B (64 bf16), swizzled
    unsigned char* Bs = smem + 16384;

    const int tid  = threadIdx.x;
    const int lane = tid & 63;
    const int w    = tid >> 6;
    const int lr   = lane & 15;
    const int lg   = lane >> 4;
    const int m0   = blockIdx.y * 128;
    const int n0   = blockIdx.x * 128;
    const int wm   = (w >> 1) * 64;
    const int wn   = (w & 1) * 64;

    f32x4 acc[4][4] = {};

    const int srow  = lane >> 3;                       // row within chunk
    const int scolb = 16 * ((lane & 7) ^ srow);        // pre-swizzled source col byte

    const int nk = K >> 6;
    for (int kt = 0; kt < nk; ++kt) {
        __syncthreads();
        const long kbyte = (long)kt * 128;
        #pragma unroll
        for (int i = 0; i < 4; ++i) {
            const int c   = w * 4 + i;
            const int row = c * 8 + srow;
            const unsigned char* srcA =
                (const unsigned char*)A + (long)(m0 + row) * (K * 2) + kbyte + scolb;
            __builtin_amdgcn_global_load_lds(AS1(srcA), AS3(As + c * 1024), 16, 0, 0);
            const unsigned char* srcB =
                (const unsigned char*)B + (long)(n0 + row) * (K * 2) + kbyte + scolb;
            __builtin_amdgcn_global_load_lds(AS1(srcB), AS3(Bs + c * 1024), 16, 0, 0);
        }
        __syncthreads();
        #pragma unroll
        for (int kk = 0; kk < 2; ++kk) {
            bf16x8 af[4], bfr[4];
            #pragma unroll
            for (int mi = 0; mi < 4; ++mi) {
                const int row  = wm + mi * 16 + lr;
                const int colb = kk * 64 + lg * 16;
                af[mi] = *(const bf16x8*)(As + row * 128 + (colb ^ ((row & 7) << 4)));
            }
            #pragma unroll
            for (int ni = 0; ni < 4; ++ni) {
                const int row  = wn + ni * 16 + lr;
                const int colb = kk * 64 + lg * 16;
                bfr[ni] = *(const bf16x8*)(Bs + row * 128 + (colb ^ ((row & 7) << 4)));
            }
            #pragma unroll
            for (int mi = 0; mi < 4; ++mi)
                #pragma unroll
                for (int ni = 0; ni < 4; ++ni)
                    acc[mi][ni] = __builtin_amdgcn_mfma_f32_16x16x32_bf16(
                        af[mi], bfr[ni], acc[mi][ni], 0, 0, 0);
        }
    }

    #pragma unroll
    for (int mi = 0; mi < 4; ++mi) {
        #pragma unroll
        for (int ni = 0; ni < 4; ++ni) {
            const int col = n0 + wn + ni * 16 + lr;
            const float bv = bias ? bias[col] : 0.0f;
            #pragma unroll
            for (int j = 0; j < 4; ++j) {
                const int rowg = m0 + wm + mi * 16 + lg * 4 + j;
                C[(long)rowg * N + col] = acc[mi][ni][j] + bv;
            }
        }
    }
}

// ---------------- QKV post: RMSNorm(q,k) + RoPE, layout shuffle ----------------
__global__ __launch_bounds__(256) void qkv_post(
    const float* __restrict__ qkv,       // [S][NQKV]
    const int* __restrict__ positions,
    const float* __restrict__ qnw,       // [QD]
    const float* __restrict__ knw,       // [KD]
    unsigned short* __restrict__ qb,     // [NH][S][DH]
    unsigned short* __restrict__ kb,     // [NKH][S][DH]
    unsigned short* __restrict__ vt)     // [NKH][DH][S]
{
    const int s   = blockIdx.x;
    const int tid = threadIdx.x;
    const float* rowp = qkv + (long)s * NQKV;
    __shared__ float red[256];
    __shared__ float s_rq, s_rk;

    float aq = 0.f;
    for (int i = tid; i < QD; i += 256) { float v = rowp[i]; aq += v * v; }
    red[tid] = aq; __syncthreads();
    for (int off = 128; off > 0; off >>= 1) {
        if (tid < off) red[tid] += red[tid + off];
        __syncthreads();
    }
    if (tid == 0) s_rq = rsqrtf(red[0] / (float)QD + 1e-6f);
    __syncthreads();

    float ak = 0.f;
    for (int i = tid; i < KD; i += 256) { float v = rowp[QD + i]; ak += v * v; }
    red[tid] = ak; __syncthreads();
    for (int off = 128; off > 0; off >>= 1) {
        if (tid < off) red[tid] += red[tid + off];
        __syncthreads();
    }
    if (tid == 0) s_rk = rsqrtf(red[0] / (float)KD + 1e-6f);
    __syncthreads();

    const float rq  = s_rq, rk = s_rk;
    const float pos = (float)positions[s];
    const float c_lnf = 0.21586735253866598f; // ln(1e6)/64

    for (int u = tid; u < NH * 64; u += 256) {
        const int h = u >> 6, j = u & 63;
        const float inv = expf(-(float)j * c_lnf);
        float sn, cs;
        sincosf(pos * inv, &sn, &cs);
        const float x1 = rowp[h * DH + j]      * rq * qnw[h * DH + j];
        const float x2 = rowp[h * DH + 64 + j] * rq * qnw[h * DH + 64 + j];
        qb[((long)h * S_LEN + s) * DH + j]      = f2bf(x1 * cs - x2 * sn);
        qb[((long)h * S_LEN + s) * DH + 64 + j] = f2bf(x2 * cs + x1 * sn);
    }
    for (int u = tid; u < NKH * 64; u += 256) {
        const int h = u >> 6, j = u & 63;
        const float inv = expf(-(float)j * c_lnf);
        float sn, cs;
        sincosf(pos * inv, &sn, &cs);
        const float x1 = rowp[QD + h * DH + j]      * rk * knw[h * DH + j];
        const float x2 = rowp[QD + h * DH + 64 + j] * rk * knw[h * DH + 64 + j];
        kb[((long)h * S_LEN + s) * DH + j]      = f2bf(x1 * cs - x2 * sn);
        kb[((long)h * S_LEN + s) * DH + 64 + j] = f2bf(x2 * cs + x1 * sn);
    }
    for (int u = tid; u < KD; u += 256) {
        const int h = u >> 7, d = u & 127;
        vt[((long)h * DH + d) * S_LEN + s] = f2bf(rowp[QD + KD + u]);
    }
}

// ---------------- flash attention: 4 waves / (head, 32-q-row tile), kv-split ----------------
// Swapped operands: scores = mfma(K,Q), O = mfma(V,P) keep q on the lane axis -> softmax
// lane-local. Wave w handles kv tiles {w, w+4, ...}; partials merged via LDS (bf16 O).
__global__ __launch_bounds__(256, 4) void attn_fwd(
    const unsigned short* __restrict__ qb,   // [NH][S][DH]
    const unsigned short* __restrict__ kb,   // [NKH][S][DH]
    const unsigned short* __restrict__ vt,   // [NKH][DH][S]
    unsigned short* __restrict__ attnb)      // [S][QD]
{
    const int q0   = S_LEN - 32 - blockIdx.x * 32;   // longest-running blocks first
    const int h    = blockIdx.y;
    const int kh   = h / NG;
    const int tid  = threadIdx.x;
    const int w    = tid >> 6;
    const int lane = tid & 63;
    const int lq   = lane & 31;          // q (and d) lane index
    const int hi   = lane >> 5;
    const int hi8  = hi * 8;
    const int hi4  = hi * 4;

    __shared__ float sml[2][3][32];
    __shared__ __align__(16) unsigned char sO[3 * 8192];  // [wave-1][lane][64 bf16], swizzled

    const float scale = 0.08838834764831845f;
    const float RTHR  = 8.0f / 0.08838834764831845f;  // defer-max threshold (raw domain)

    // Q fragments (B-operand): Q[q0+lq][c*16 + hi*8 + e], c = 0..7
    bf16x8 qf[8];
    const unsigned short* qrow = qb + ((long)h * S_LEN + q0 + lq) * DH;
    #pragma unroll
    for (int c = 0; c < 8; ++c)
        qf[c] = *(const bf16x8*)(qrow + c * 16 + hi8);

    f32x16 o[4] = {};
    float m = -3e38f;
    float l = 0.f;

    const int ntiles = q0 / 32 + 1;
    for (int kvt = w; kvt < ntiles; kvt += 4) {
        const int kb0 = kvt * 32;

        // ---- QK^T (swapped): sc[col=q][reg-row=k] ----
        bf16x8 kf[8];
        const unsigned short* krow = kb + ((long)kh * S_LEN + kb0 + lq) * DH;
        #pragma unroll
        for (int c = 0; c < 8; ++c)
            kf[c] = *(const bf16x8*)(krow + c * 16 + hi8);
        f32x16 sc = {};
        #pragma unroll
        for (int c = 0; c < 8; ++c)
            sc = __builtin_amdgcn_mfma_f32_32x32x16_bf16(kf[c], qf[c], sc, 0, 0, 0);

        // ---- mask (diagonal tile only) ----
        float s[16];
        if (kvt == ntiles - 1) {
            #pragma unroll
            for (int r = 0; r < 16; ++r) {
                const int kr = (r & 3) + 8 * (r >> 2) + hi4;
                s[r] = (kr > lq) ? -3e38f : sc[r];
            }
        } else {
            #pragma unroll
            for (int r = 0; r < 16; ++r) s[r] = sc[r];
        }

        // ---- online softmax, lane-local ----
        float mx = s[0];
        #pragma unroll
        for (int r = 1; r < 16; ++r) mx = fmaxf(mx, s[r]);
        mx = fmaxf(mx, __shfl_xor(mx, 32));

        if (!__all(mx <= m + RTHR)) {
            const float nm  = fmaxf(m, mx);
            const float fac = __expf((m - nm) * scale);
            l *= fac;
            #pragma unroll
            for (int d0 = 0; d0 < 4; ++d0)
                #pragma unroll
                for (int r = 0; r < 16; ++r) o[d0][r] *= fac;
            m = nm;
        }

        float p[16];
        float ps = 0.f;
        #pragma unroll
        for (int r = 0; r < 16; ++r) {
            p[r] = __expf((s[r] - m) * scale);
            ps += p[r];
        }
        ps += __shfl_xor(ps, 32);
        l += ps;

        // ---- P (f32, k in regs) -> PV B-fragments (k on ctr axis) ----
        unsigned pa01 = pkbf(p[0],  p[1]),  pa23 = pkbf(p[2],  p[3]);
        unsigned pb01 = pkbf(p[4],  p[5]),  pb23 = pkbf(p[6],  p[7]);
        unsigned pc01 = pkbf(p[8],  p[9]),  pc23 = pkbf(p[10], p[11]);
        unsigned pd01 = pkbf(p[12], p[13]), pd23 = pkbf(p[14], p[15]);
        unsigned xa01 = __shfl_xor((int)pa01, 32), xa23 = __shfl_xor((int)pa23, 32);
        unsigned xb01 = __shfl_xor((int)pb01, 32), xb23 = __shfl_xor((int)pb23, 32);
        unsigned xc01 = __shfl_xor((int)pc01, 32), xc23 = __shfl_xor((int)pc23, 32);
        unsigned xd01 = __shfl_xor((int)pd01, 32), xd23 = __shfl_xor((int)pd23, 32);

        union { unsigned u[4]; bf16x8 v; } pf0, pf1;
        pf0.u[0] = hi ? xb01 : pa01;
        pf0.u[1] = hi ? xb23 : pa23;
        pf0.u[2] = hi ? pb01 : xa01;
        pf0.u[3] = hi ? pb23 : xa23;
        pf1.u[0] = hi ? xd01 : pc01;
        pf1.u[1] = hi ? xd23 : pc23;
        pf1.u[2] = hi ? pd01 : xc01;
        pf1.u[3] = hi ? pd23 : xc23;

        // ---- PV (swapped): o[col=q][reg-row=d] ----
        #pragma unroll
        for (int d0 = 0; d0 < 4; ++d0) {
            const unsigned short* vrow =
                vt + ((long)kh * DH + d0 * 32 + lq) * S_LEN + kb0 + hi8;
            bf16x8 vf0 = *(const bf16x8*)vrow;
            bf16x8 vf1 = *(const bf16x8*)(vrow + 16);
            o[d0] = __builtin_amdgcn_mfma_f32_32x32x16_bf16(vf0, pf0.v, o[d0], 0, 0, 0);
            o[d0] = __builtin_amdgcn_mfma_f32_32x32x16_bf16(vf1, pf1.v, o[d0], 0, 0, 0);
        }
    }

    // ---- waves 1..3: publish partials (m, l, O as bf16, swizzled) ----
    if (w != 0) {
        if (hi == 0) {
            sml[0][w - 1][lq] = m;
            sml[1][w - 1][lq] = l;
        }
        unsigned char* dst = sO + (w - 1) * 8192 + lane * 128;
        #pragma unroll
        for (int c = 0; c < 8; ++c) {
            const int d0 = c >> 1, rb = (c & 1) * 8;
            uint4 pk;
            pk.x = pkbf(o[d0][rb + 0], o[d0][rb + 1]);
            pk.y = pkbf(o[d0][rb + 2], o[d0][rb + 3]);
            pk.z = pkbf(o[d0][rb + 4], o[d0][rb + 5]);
            pk.w = pkbf(o[d0][rb + 6], o[d0][rb + 7]);
            *(uint4*)(dst + ((c * 16) ^ ((lane & 7) << 4))) = pk;
        }
    }
    __syncthreads();
    if (w != 0) return;

    // ---- wave 0: merge partials ----
    float mw[3], lw[3];
    float M = m;
    #pragma unroll
    for (int pw = 0; pw < 3; ++pw) {
        mw[pw] = sml[0][pw][lq];
        lw[pw] = sml[1][pw][lq];
        M = fmaxf(M, mw[pw]);
    }
    const float fac0 = __expf((m - M) * scale);
    float ltot = l * fac0;
    #pragma unroll
    for (int d0 = 0; d0 < 4; ++d0)
        #pragma unroll
        for (int r = 0; r < 16; ++r) o[d0][r] *= fac0;
    #pragma unroll
    for (int pw = 0; pw < 3; ++pw) {
        const float f = __expf((mw[pw] - M) * scale);
        ltot += lw[pw] * f;
        const unsigned char* src = sO + pw * 8192 + lane * 128;
        #pragma unroll
        for (int c = 0; c < 8; ++c) {
            const int d0 = c >> 1, rb = (c & 1) * 8;
            uint4 d = *(const uint4*)(src + ((c * 16) ^ ((lane & 7) << 4)));
            o[d0][rb + 0] += f * bflo(d.x); o[d0][rb + 1] += f * bfhi(d.x);
            o[d0][rb + 2] += f * bflo(d.y); o[d0][rb + 3] += f * bfhi(d.y);
            o[d0][rb + 4] += f * bflo(d.z); o[d0][rb + 5] += f * bfhi(d.z);
            o[d0][rb + 6] += f * bflo(d.w); o[d0][rb + 7] += f * bfhi(d.w);
        }
    }

    // ---- epilogue: out[q0+lq][h*DH + d], d = d0*32 + 8g + hi4 + 0..3 ----
    const float rl = 1.0f / ltot;
    unsigned short* orow = attnb + (long)(q0 + lq) * QD + h * DH;
    #pragma unroll
    for (int d0 = 0; d0 < 4; ++d0) {
        #pragma unroll
        for (int g = 0; g < 4; ++g) {
            ushort4 s4;
            s4.x = f2bf(o[d0][4 * g + 0] * rl);
            s4.y = f2bf(o[d0][4 * g + 1] * rl);
            s4.z = f2bf(o[d0][4 * g + 2] * rl);
            s4.w = f2bf(o[d0][4 * g + 3] * rl);
            *(ushort4*)(orow + d0 * 32 + 8 * g + hi4) = s4;
        }
    }
}

// ---------------- launch ----------------
extern "C" void kernel_launch(void* const* d_in, const int* in_sizes, int n_in,
                              void* d_out, int out_size, void* d_ws, size_t ws_size,
                              hipStream_t stream) {
    const int*   positions = (const int*)d_in[0];
    const float* hidden    = (const float*)d_in[1];
    const float* qkv_w     = (const float*)d_in[2];
    const float* qkv_b     = (const float*)d_in[3];
    const float* qnw       = (const float*)d_in[4];
    const float* knw       = (const float*)d_in[5];
    const float* o_w       = (const float*)d_in[6];
    float* out = (float*)d_out;

    unsigned char* ws = (unsigned char*)d_ws;
    unsigned short* hb    = (unsigned short*)(ws);               // 14,680,064 B
    unsigned short* w1    = (unsigned short*)(ws + 14680064);    // 33,030,144 B
    float*          qkvf  = (float*)(ws + 47710208);             // 37,748,736 B
    unsigned short* qbuf  = (unsigned short*)(ws + 85458944);    // 14,680,064 B
    unsigned short* kbuf  = (unsigned short*)(ws + 100139008);   //  2,097,152 B
    unsigned short* vtb   = (unsigned short*)(ws + 102236160);   //  2,097,152 B
    unsigned short* attnb = (unsigned short*)(ws);               // reuse hb
    unsigned short* w2    = (unsigned short*)(ws + 14680064);    // reuse w1

    cvt_f32_bf16<<<(S_LEN * HIDDEN / 4 + 255) / 256, 256, 0, stream>>>(hidden, hb, S_LEN * HIDDEN / 4);
    cvt_f32_bf16<<<(NQKV * HIDDEN / 4 + 255) / 256, 256, 0, stream>>>(qkv_w, w1, NQKV * HIDDEN / 4);
    gemm_bf16<<<dim3(NQKV / 128, S_LEN / 128), 256, 0, stream>>>(hb, w1, qkvf, qkv_b, S_LEN, NQKV, HIDDEN);
    qkv_post<<<S_LEN, 256, 0, stream>>>(qkvf, positions, qnw, knw, qbuf, kbuf, vtb);
    attn_fwd<<<dim3(S_LEN / 32, NH), 256, 0, stream>>>(qbuf, kbuf, vtb, attnb);
    cvt_f32_bf16<<<(HIDDEN * QD / 4 + 255) / 256, 256, 0, stream>>>(o_w, w2, HIDDEN * QD / 4);
    gemm_bf16<<<dim3(HIDDEN / 128, S_LEN / 128), 256, 0, stream>>>(attnb, w2, out, nullptr, S_LEN, HIDDEN, QD);
}

// Round 4
// 423.336 us; speedup vs baseline: 1.0443x; 1.0443x over previous
//
#include <hip/hip_runtime.h>
#include <hip/hip_bf16.h>
#include <stdint.h>

#define S_LEN 2048
#define HIDDEN 3584
#define NH 28
#define NKH 4
#define DH 128
#define NG 7          // NH / NKH
#define NQKV 4608     // (NH + 2*NKH) * DH
#define QD 3584       // NH*DH
#define KD 512        // NKH*DH
#define NSPLIT 2
#define PREC 4160     // floats per partial record: 32*128 O + 32 m + 32 l

using bf16x8 = __attribute__((ext_vector_type(8))) __bf16;
using f32x4  = __attribute__((ext_vector_type(4))) float;
using f32x16 = __attribute__((ext_vector_type(16))) float;

#define AS3(p) ((__attribute__((address_space(3))) void*)(p))
#define AS1(p) ((const __attribute__((address_space(1))) void*)(p))

__device__ __forceinline__ unsigned short f2bf(float f) {
    unsigned u = __float_as_uint(f);
    u += 0x7FFFu + ((u >> 16) & 1u);
    return (unsigned short)(u >> 16);
}
__device__ __forceinline__ unsigned pkbf(float a, float b) {
    return (unsigned)f2bf(a) | ((unsigned)f2bf(b) << 16);
}

// ---------------- f32 -> bf16 convert (vectorized) ----------------
__global__ void cvt_f32_bf16(const float* __restrict__ in,
                             unsigned short* __restrict__ out, int n4) {
    int i = blockIdx.x * blockDim.x + threadIdx.x;
    if (i >= n4) return;
    float4 v = ((const float4*)in)[i];
    ushort4 o;
    o.x = f2bf(v.x); o.y = f2bf(v.y); o.z = f2bf(v.z); o.w = f2bf(v.w);
    ((ushort4*)out)[i] = o;
}

// ---------------- bf16 GEMM: C[M][N] = A[M][K] * B[N][K]^T (+bias) ----------------
__global__ __launch_bounds__(256) void gemm_bf16(
    const unsigned short* __restrict__ A,
    const unsigned short* __restrict__ B,
    float* __restrict__ C,
    const float* __restrict__ bias,
    int M, int N, int K)
{
    __shared__ __align__(16) unsigned char smem[32768];
    unsigned char* As = smem;           // 128 rows x 128B (64 bf16), swizzled
    unsigned char* Bs = smem + 16384;

    const int tid  = threadIdx.x;
    const int lane = tid & 63;
    const int w    = tid >> 6;
    const int lr   = lane & 15;
    const int lg   = lane >> 4;
    const int m0   = blockIdx.y * 128;
    const int n0   = blockIdx.x * 128;
    const int wm   = (w >> 1) * 64;
    const int wn   = (w & 1) * 64;

    f32x4 acc[4][4] = {};

    const int srow  = lane >> 3;                       // row within chunk
    const int scolb = 16 * ((lane & 7) ^ srow);        // pre-swizzled source col byte

    const int nk = K >> 6;
    for (int kt = 0; kt < nk; ++kt) {
        __syncthreads();
        const long kbyte = (long)kt * 128;
        #pragma unroll
        for (int i = 0; i < 4; ++i) {
            const int c   = w * 4 + i;
            const int row = c * 8 + srow;
            const unsigned char* srcA =
                (const unsigned char*)A + (long)(m0 + row) * (K * 2) + kbyte + scolb;
            __builtin_amdgcn_global_load_lds(AS1(srcA), AS3(As + c * 1024), 16, 0, 0);
            const unsigned char* srcB =
                (const unsigned char*)B + (long)(n0 + row) * (K * 2) + kbyte + scolb;
            __builtin_amdgcn_global_load_lds(AS1(srcB), AS3(Bs + c * 1024), 16, 0, 0);
        }
        __syncthreads();
        #pragma unroll
        for (int kk = 0; kk < 2; ++kk) {
            bf16x8 af[4], bfr[4];
            #pragma unroll
            for (int mi = 0; mi < 4; ++mi) {
                const int row  = wm + mi * 16 + lr;
                const int colb = kk * 64 + lg * 16;
                af[mi] = *(const bf16x8*)(As + row * 128 + (colb ^ ((row & 7) << 4)));
            }
            #pragma unroll
            for (int ni = 0; ni < 4; ++ni) {
                const int row  = wn + ni * 16 + lr;
                const int colb = kk * 64 + lg * 16;
                bfr[ni] = *(const bf16x8*)(Bs + row * 128 + (colb ^ ((row & 7) << 4)));
            }
            #pragma unroll
            for (int mi = 0; mi < 4; ++mi)
                #pragma unroll
                for (int ni = 0; ni < 4; ++ni)
                    acc[mi][ni] = __builtin_amdgcn_mfma_f32_16x16x32_bf16(
                        af[mi], bfr[ni], acc[mi][ni], 0, 0, 0);
        }
    }

    #pragma unroll
    for (int mi = 0; mi < 4; ++mi) {
        #pragma unroll
        for (int ni = 0; ni < 4; ++ni) {
            const int col = n0 + wn + ni * 16 + lr;
            const float bv = bias ? bias[col] : 0.0f;
            #pragma unroll
            for (int j = 0; j < 4; ++j) {
                const int rowg = m0 + wm + mi * 16 + lg * 4 + j;
                C[(long)rowg * N + col] = acc[mi][ni][j] + bv;
            }
        }
    }
}

// ---------------- QKV post: RMSNorm(q,k) + RoPE, layout shuffle ----------------
__global__ __launch_bounds__(256) void qkv_post(
    const float* __restrict__ qkv,       // [S][NQKV]
    const int* __restrict__ positions,
    const float* __restrict__ qnw,       // [QD]
    const float* __restrict__ knw,       // [KD]
    unsigned short* __restrict__ qb,     // [NH][S][DH]
    unsigned short* __restrict__ kb,     // [NKH][S][DH]
    unsigned short* __restrict__ vt)     // [NKH][DH][S]
{
    const int s   = blockIdx.x;
    const int tid = threadIdx.x;
    const float* rowp = qkv + (long)s * NQKV;
    __shared__ float red[256];
    __shared__ float s_rq, s_rk;

    float aq = 0.f;
    for (int i = tid; i < QD; i += 256) { float v = rowp[i]; aq += v * v; }
    red[tid] = aq; __syncthreads();
    for (int off = 128; off > 0; off >>= 1) {
        if (tid < off) red[tid] += red[tid + off];
        __syncthreads();
    }
    if (tid == 0) s_rq = rsqrtf(red[0] / (float)QD + 1e-6f);
    __syncthreads();

    float ak = 0.f;
    for (int i = tid; i < KD; i += 256) { float v = rowp[QD + i]; ak += v * v; }
    red[tid] = ak; __syncthreads();
    for (int off = 128; off > 0; off >>= 1) {
        if (tid < off) red[tid] += red[tid + off];
        __syncthreads();
    }
    if (tid == 0) s_rk = rsqrtf(red[0] / (float)KD + 1e-6f);
    __syncthreads();

    const float rq  = s_rq, rk = s_rk;
    const float pos = (float)positions[s];
    const float c_lnf = 0.21586735253866598f; // ln(1e6)/64

    for (int u = tid; u < NH * 64; u += 256) {
        const int h = u >> 6, j = u & 63;
        const float inv = expf(-(float)j * c_lnf);
        float sn, cs;
        sincosf(pos * inv, &sn, &cs);
        const float x1 = rowp[h * DH + j]      * rq * qnw[h * DH + j];
        const float x2 = rowp[h * DH + 64 + j] * rq * qnw[h * DH + 64 + j];
        qb[((long)h * S_LEN + s) * DH + j]      = f2bf(x1 * cs - x2 * sn);
        qb[((long)h * S_LEN + s) * DH + 64 + j] = f2bf(x2 * cs + x1 * sn);
    }
    for (int u = tid; u < NKH * 64; u += 256) {
        const int h = u >> 6, j = u & 63;
        const float inv = expf(-(float)j * c_lnf);
        float sn, cs;
        sincosf(pos * inv, &sn, &cs);
        const float x1 = rowp[QD + h * DH + j]      * rk * knw[h * DH + j];
        const float x2 = rowp[QD + h * DH + 64 + j] * rk * knw[h * DH + 64 + j];
        kb[((long)h * S_LEN + s) * DH + j]      = f2bf(x1 * cs - x2 * sn);
        kb[((long)h * S_LEN + s) * DH + 64 + j] = f2bf(x2 * cs + x1 * sn);
    }
    for (int u = tid; u < KD; u += 256) {
        const int h = u >> 7, d = u & 127;
        vt[((long)h * DH + d) * S_LEN + s] = f2bf(rowp[QD + KD + u]);
    }
}

// ---------------- flash attention split: 1 wave / (head, 32-q-rows, kv-chunk) ----------------
// Swapped operands: scores = mfma(K,Q), O = mfma(V,P) keep q on the lane axis -> softmax
// lane-local, no LDS, no barriers. Chunk c handles kv tiles {c, c+NSPLIT, ...} (interleaved
// for causal load balance); f32 partials (O, m, l) go to pbuf for the combine kernel.
__global__ __launch_bounds__(64) void attn_split(
    const unsigned short* __restrict__ qb,   // [NH][S][DH]
    const unsigned short* __restrict__ kb,   // [NKH][S][DH]
    const unsigned short* __restrict__ vt,   // [NKH][DH][S]
    float* __restrict__ pbuf)                // [NSPLIT][NH][64] records of PREC floats
{
    const int qt   = blockIdx.x;
    const int q0   = S_LEN - 32 - qt * 32;   // longest-running blocks first
    const int h    = blockIdx.y;
    const int ck   = blockIdx.z;
    const int kh   = h / NG;
    const int lane = threadIdx.x;
    const int lq   = lane & 31;          // q (and d) lane index
    const int hi   = lane >> 5;
    const int hi8  = hi * 8;
    const int hi4  = hi * 4;

    const float scale = 0.08838834764831845f;
    const float RTHR  = 8.0f / 0.08838834764831845f;  // defer-max threshold (raw domain)

    // Q fragments (B-operand): Q[q0+lq][c*16 + hi*8 + e], c = 0..7
    bf16x8 qf[8];
    const unsigned short* qrow = qb + ((long)h * S_LEN + q0 + lq) * DH;
    #pragma unroll
    for (int c = 0; c < 8; ++c)
        qf[c] = *(const bf16x8*)(qrow + c * 16 + hi8);

    f32x16 o[4] = {};
    float m = -3e38f;
    float l = 0.f;

    const int ntiles = q0 / 32 + 1;
    for (int kvt = ck; kvt < ntiles; kvt += NSPLIT) {
        const int kb0 = kvt * 32;

        // ---- QK^T (swapped): sc[col=q][reg-row=k] ----
        bf16x8 kf[8];
        const unsigned short* krow = kb + ((long)kh * S_LEN + kb0 + lq) * DH;
        #pragma unroll
        for (int c = 0; c < 8; ++c)
            kf[c] = *(const bf16x8*)(krow + c * 16 + hi8);
        f32x16 sc = {};
        #pragma unroll
        for (int c = 0; c < 8; ++c)
            sc = __builtin_amdgcn_mfma_f32_32x32x16_bf16(kf[c], qf[c], sc, 0, 0, 0);

        // ---- mask (diagonal tile only) ----
        float s[16];
        if (kvt == ntiles - 1) {
            #pragma unroll
            for (int r = 0; r < 16; ++r) {
                const int kr = (r & 3) + 8 * (r >> 2) + hi4;
                s[r] = (kr > lq) ? -3e38f : sc[r];
            }
        } else {
            #pragma unroll
            for (int r = 0; r < 16; ++r) s[r] = sc[r];
        }

        // ---- online softmax, lane-local ----
        float mx = s[0];
        #pragma unroll
        for (int r = 1; r < 16; ++r) mx = fmaxf(mx, s[r]);
        mx = fmaxf(mx, __shfl_xor(mx, 32));

        if (!__all(mx <= m + RTHR)) {
            const float nm  = fmaxf(m, mx);
            const float fac = __expf((m - nm) * scale);
            l *= fac;
            #pragma unroll
            for (int d0 = 0; d0 < 4; ++d0)
                #pragma unroll
                for (int r = 0; r < 16; ++r) o[d0][r] *= fac;
            m = nm;
        }

        float p[16];
        float ps = 0.f;
        #pragma unroll
        for (int r = 0; r < 16; ++r) {
            p[r] = __expf((s[r] - m) * scale);
            ps += p[r];
        }
        ps += __shfl_xor(ps, 32);
        l += ps;

        // ---- P (f32, k in regs) -> PV B-fragments (k on ctr axis) ----
        unsigned pa01 = pkbf(p[0],  p[1]),  pa23 = pkbf(p[2],  p[3]);
        unsigned pb01 = pkbf(p[4],  p[5]),  pb23 = pkbf(p[6],  p[7]);
        unsigned pc01 = pkbf(p[8],  p[9]),  pc23 = pkbf(p[10], p[11]);
        unsigned pd01 = pkbf(p[12], p[13]), pd23 = pkbf(p[14], p[15]);
        unsigned xa01 = __shfl_xor((int)pa01, 32), xa23 = __shfl_xor((int)pa23, 32);
        unsigned xb01 = __shfl_xor((int)pb01, 32), xb23 = __shfl_xor((int)pb23, 32);
        unsigned xc01 = __shfl_xor((int)pc01, 32), xc23 = __shfl_xor((int)pc23, 32);
        unsigned xd01 = __shfl_xor((int)pd01, 32), xd23 = __shfl_xor((int)pd23, 32);

        union { unsigned u[4]; bf16x8 v; } pf0, pf1;
        pf0.u[0] = hi ? xb01 : pa01;
        pf0.u[1] = hi ? xb23 : pa23;
        pf0.u[2] = hi ? pb01 : xa01;
        pf0.u[3] = hi ? pb23 : xa23;
        pf1.u[0] = hi ? xd01 : pc01;
        pf1.u[1] = hi ? xd23 : pc23;
        pf1.u[2] = hi ? pd01 : xc01;
        pf1.u[3] = hi ? pd23 : xc23;

        // ---- PV (swapped): o[col=q][reg-row=d] ----
        #pragma unroll
        for (int d0 = 0; d0 < 4; ++d0) {
            const unsigned short* vrow =
                vt + ((long)kh * DH + d0 * 32 + lq) * S_LEN + kb0 + hi8;
            bf16x8 vf0 = *(const bf16x8*)vrow;
            bf16x8 vf1 = *(const bf16x8*)(vrow + 16);
            o[d0] = __builtin_amdgcn_mfma_f32_32x32x16_bf16(vf0, pf0.v, o[d0], 0, 0, 0);
            o[d0] = __builtin_amdgcn_mfma_f32_32x32x16_bf16(vf1, pf1.v, o[d0], 0, 0, 0);
        }
    }

    // ---- write f32 partials: O[q][d], then m[32], l[32] ----
    float* rec = pbuf + (long)((ck * NH + h) * 64 + qt) * PREC;
    #pragma unroll
    for (int d0 = 0; d0 < 4; ++d0) {
        #pragma unroll
        for (int g = 0; g < 4; ++g) {
            float4 s4;
            s4.x = o[d0][4 * g + 0];
            s4.y = o[d0][4 * g + 1];
            s4.z = o[d0][4 * g + 2];
            s4.w = o[d0][4 * g + 3];
            *(float4*)(rec + lq * DH + d0 * 32 + 8 * g + hi4) = s4;
        }
    }
    if (hi == 0) {
        rec[4096 + lq] = m;
        rec[4128 + lq] = l;
    }
}

// ---------------- combine partials -> bf16 attn output ----------------
__global__ __launch_bounds__(256) void attn_combine(
    const float* __restrict__ pbuf,
    unsigned short* __restrict__ attnb)      // [S][QD]
{
    const int qt  = blockIdx.x;
    const int q0  = S_LEN - 32 - qt * 32;
    const int h   = blockIdx.y;
    const int tid = threadIdx.x;
    const int q   = tid >> 3;
    const int dg  = (tid & 7) * 16;
    const float scale = 0.08838834764831845f;

    const float* r0 = pbuf + (long)((0 * NH + h) * 64 + qt) * PREC;
    const float* r1 = pbuf + (long)((1 * NH + h) * 64 + qt) * PREC;
    const float m0 = r0[4096 + q], l0 = r0[4128 + q];
    const float m1 = r1[4096 + q], l1 = r1[4128 + q];
    const float M  = fmaxf(m0, m1);
    const float f0 = __expf((m0 - M) * scale);
    const float f1 = __expf((m1 - M) * scale);
    const float rl = 1.0f / (l0 * f0 + l1 * f1);

    unsigned short* orow = attnb + (long)(q0 + q) * QD + h * DH + dg;
    #pragma unroll
    for (int i = 0; i < 4; ++i) {
        float4 a = *(const float4*)(r0 + q * DH + dg + i * 4);
        float4 b = *(const float4*)(r1 + q * DH + dg + i * 4);
        ushort4 s4;
        s4.x = f2bf((f0 * a.x + f1 * b.x) * rl);
        s4.y = f2bf((f0 * a.y + f1 * b.y) * rl);
        s4.z = f2bf((f0 * a.z + f1 * b.z) * rl);
        s4.w = f2bf((f0 * a.w + f1 * b.w) * rl);
        *(ushort4*)(orow + i * 4) = s4;
    }
}

// ---------------- launch ----------------
extern "C" void kernel_launch(void* const* d_in, const int* in_sizes, int n_in,
                              void* d_out, int out_size, void* d_ws, size_t ws_size,
                              hipStream_t stream) {
    const int*   positions = (const int*)d_in[0];
    const float* hidden    = (const float*)d_in[1];
    const float* qkv_w     = (const float*)d_in[2];
    const float* qkv_b     = (const float*)d_in[3];
    const float* qnw       = (const float*)d_in[4];
    const float* knw       = (const float*)d_in[5];
    const float* o_w       = (const float*)d_in[6];
    float* out = (float*)d_out;

    unsigned char* ws = (unsigned char*)d_ws;
    unsigned short* hb    = (unsigned short*)(ws);               // 14,680,064 B
    unsigned short* w1    = (unsigned short*)(ws + 14680064);    // 33,030,144 B
    float*          qkvf  = (float*)(ws + 47710208);             // 37,748,736 B
    unsigned short* qbuf  = (unsigned short*)(ws + 85458944);    // 14,680,064 B
    unsigned short* kbuf  = (unsigned short*)(ws + 100139008);   //  2,097,152 B
    unsigned short* vtb   = (unsigned short*)(ws + 102236160);   //  2,097,152 B
    unsigned short* attnb = (unsigned short*)(ws);               // reuse hb (dead after GEMM1)
    float*          pbuf  = (float*)(ws + 14680064);             // 59,637,760 B (w1+qkvf region)
    unsigned short* w2    = (unsigned short*)(ws + 14680064);    // reuse after combine

    cvt_f32_bf16<<<(S_LEN * HIDDEN / 4 + 255) / 256, 256, 0, stream>>>(hidden, hb, S_LEN * HIDDEN / 4);
    cvt_f32_bf16<<<(NQKV * HIDDEN / 4 + 255) / 256, 256, 0, stream>>>(qkv_w, w1, NQKV * HIDDEN / 4);
    gemm_bf16<<<dim3(NQKV / 128, S_LEN / 128), 256, 0, stream>>>(hb, w1, qkvf, qkv_b, S_LEN, NQKV, HIDDEN);
    qkv_post<<<S_LEN, 256, 0, stream>>>(qkvf, positions, qnw, knw, qbuf, kbuf, vtb);
    attn_split<<<dim3(S_LEN / 32, NH, NSPLIT), 64, 0, stream>>>(qbuf, kbuf, vtb, pbuf);
    attn_combine<<<dim3(S_LEN / 32, NH), 256, 0, stream>>>(pbuf, attnb);
    cvt_f32_bf16<<<(HIDDEN * QD / 4 + 255) / 256, 256, 0, stream>>>(o_w, w2, HIDDEN * QD / 4);
    gemm_bf16<<<dim3(HIDDEN / 128, S_LEN / 128), 256, 0, stream>>>(attnb, w2, out, nullptr, S_LEN, HIDDEN, QD);
}

// Round 5
// 331.174 us; speedup vs baseline: 1.3349x; 1.2783x over previous
//
#include <hip/hip_runtime.h>
#include <hip/hip_bf16.h>
#include <stdint.h>

#define S_LEN 2048
#define HIDDEN 3584
#define NH 28
#define NKH 4
#define DH 128
#define NG 7          // NH / NKH
#define NQKV 4608     // (NH + 2*NKH) * DH
#define QD 3584       // NH*DH
#define KD 512        // NKH*DH

using bf16x8 = __attribute__((ext_vector_type(8))) __bf16;
using f32x4  = __attribute__((ext_vector_type(4))) float;
using f32x16 = __attribute__((ext_vector_type(16))) float;

#define AS3(p) ((__attribute__((address_space(3))) void*)(p))
#define AS1(p) ((const __attribute__((address_space(1))) void*)(p))

__device__ __forceinline__ unsigned short f2bf(float f) {
    unsigned u = __float_as_uint(f);
    u += 0x7FFFu + ((u >> 16) & 1u);
    return (unsigned short)(u >> 16);
}
__device__ __forceinline__ unsigned pkbf(float a, float b) {
    return (unsigned)f2bf(a) | ((unsigned)f2bf(b) << 16);
}

// ---------------- f32 -> bf16 convert (vectorized) ----------------
__global__ void cvt_f32_bf16(const float* __restrict__ in,
                             unsigned short* __restrict__ out, int n4) {
    int i = blockIdx.x * blockDim.x + threadIdx.x;
    if (i >= n4) return;
    float4 v = ((const float4*)in)[i];
    ushort4 o;
    o.x = f2bf(v.x); o.y = f2bf(v.y); o.z = f2bf(v.z); o.w = f2bf(v.w);
    ((ushort4*)out)[i] = o;
}

// ---------------- bf16 GEMM: C[M][N] = A[M][K] * B[N][K]^T (+bias) ----------------
__global__ __launch_bounds__(256) void gemm_bf16(
    const unsigned short* __restrict__ A,
    const unsigned short* __restrict__ B,
    float* __restrict__ C,
    const float* __restrict__ bias,
    int M, int N, int K)
{
    __shared__ __align__(16) unsigned char smem[32768];
    unsigned char* As = smem;           // 128 rows x 128B (64 bf16), swizzled
    unsigned char* Bs = smem + 16384;

    const int tid  = threadIdx.x;
    const int lane = tid & 63;
    const int w    = tid >> 6;
    const int lr   = lane & 15;
    const int lg   = lane >> 4;
    const int m0   = blockIdx.y * 128;
    const int n0   = blockIdx.x * 128;
    const int wm   = (w >> 1) * 64;
    const int wn   = (w & 1) * 64;

    f32x4 acc[4][4] = {};

    const int srow  = lane >> 3;                       // row within chunk
    const int scolb = 16 * ((lane & 7) ^ srow);        // pre-swizzled source col byte

    const int nk = K >> 6;
    for (int kt = 0; kt < nk; ++kt) {
        __syncthreads();
        const long kbyte = (long)kt * 128;
        #pragma unroll
        for (int i = 0; i < 4; ++i) {
            const int c   = w * 4 + i;
            const int row = c * 8 + srow;
            const unsigned char* srcA =
                (const unsigned char*)A + (long)(m0 + row) * (K * 2) + kbyte + scolb;
            __builtin_amdgcn_global_load_lds(AS1(srcA), AS3(As + c * 1024), 16, 0, 0);
            const unsigned char* srcB =
                (const unsigned char*)B + (long)(n0 + row) * (K * 2) + kbyte + scolb;
            __builtin_amdgcn_global_load_lds(AS1(srcB), AS3(Bs + c * 1024), 16, 0, 0);
        }
        __syncthreads();
        #pragma unroll
        for (int kk = 0; kk < 2; ++kk) {
            bf16x8 af[4], bfr[4];
            #pragma unroll
            for (int mi = 0; mi < 4; ++mi) {
                const int row  = wm + mi * 16 + lr;
                const int colb = kk * 64 + lg * 16;
                af[mi] = *(const bf16x8*)(As + row * 128 + (colb ^ ((row & 7) << 4)));
            }
            #pragma unroll
            for (int ni = 0; ni < 4; ++ni) {
                const int row  = wn + ni * 16 + lr;
                const int colb = kk * 64 + lg * 16;
                bfr[ni] = *(const bf16x8*)(Bs + row * 128 + (colb ^ ((row & 7) << 4)));
            }
            #pragma unroll
            for (int mi = 0; mi < 4; ++mi)
                #pragma unroll
                for (int ni = 0; ni < 4; ++ni)
                    acc[mi][ni] = __builtin_amdgcn_mfma_f32_16x16x32_bf16(
                        af[mi], bfr[ni], acc[mi][ni], 0, 0, 0);
        }
    }

    #pragma unroll
    for (int mi = 0; mi < 4; ++mi) {
        #pragma unroll
        for (int ni = 0; ni < 4; ++ni) {
            const int col = n0 + wn + ni * 16 + lr;
            const float bv = bias ? bias[col] : 0.0f;
            #pragma unroll
            for (int j = 0; j < 4; ++j) {
                const int rowg = m0 + wm + mi * 16 + lg * 4 + j;
                C[(long)rowg * N + col] = acc[mi][ni][j] + bv;
            }
        }
    }
}

// ---------------- QKV post: RMSNorm(q,k) + RoPE, layout shuffle ----------------
__global__ __launch_bounds__(256) void qkv_post(
    const float* __restrict__ qkv,       // [S][NQKV]
    const int* __restrict__ positions,
    const float* __restrict__ qnw,       // [QD]
    const float* __restrict__ knw,       // [KD]
    unsigned short* __restrict__ qb,     // [NH][S][DH]
    unsigned short* __restrict__ kb,     // [NKH][S][DH]
    unsigned short* __restrict__ vt2)    // [NKH][S/32][DH][32]
{
    const int s   = blockIdx.x;
    const int tid = threadIdx.x;
    const float* rowp = qkv + (long)s * NQKV;
    __shared__ float red[256];
    __shared__ float s_rq, s_rk;

    float aq = 0.f;
    for (int i = tid; i < QD; i += 256) { float v = rowp[i]; aq += v * v; }
    red[tid] = aq; __syncthreads();
    for (int off = 128; off > 0; off >>= 1) {
        if (tid < off) red[tid] += red[tid + off];
        __syncthreads();
    }
    if (tid == 0) s_rq = rsqrtf(red[0] / (float)QD + 1e-6f);
    __syncthreads();

    float ak = 0.f;
    for (int i = tid; i < KD; i += 256) { float v = rowp[QD + i]; ak += v * v; }
    red[tid] = ak; __syncthreads();
    for (int off = 128; off > 0; off >>= 1) {
        if (tid < off) red[tid] += red[tid + off];
        __syncthreads();
    }
    if (tid == 0) s_rk = rsqrtf(red[0] / (float)KD + 1e-6f);
    __syncthreads();

    const float rq  = s_rq, rk = s_rk;
    const float pos = (float)positions[s];
    const float c_lnf = 0.21586735253866598f; // ln(1e6)/64

    for (int u = tid; u < NH * 64; u += 256) {
        const int h = u >> 6, j = u & 63;
        const float inv = expf(-(float)j * c_lnf);
        float sn, cs;
        sincosf(pos * inv, &sn, &cs);
        const float x1 = rowp[h * DH + j]      * rq * qnw[h * DH + j];
        const float x2 = rowp[h * DH + 64 + j] * rq * qnw[h * DH + 64 + j];
        qb[((long)h * S_LEN + s) * DH + j]      = f2bf(x1 * cs - x2 * sn);
        qb[((long)h * S_LEN + s) * DH + 64 + j] = f2bf(x2 * cs + x1 * sn);
    }
    for (int u = tid; u < NKH * 64; u += 256) {
        const int h = u >> 6, j = u & 63;
        const float inv = expf(-(float)j * c_lnf);
        float sn, cs;
        sincosf(pos * inv, &sn, &cs);
        const float x1 = rowp[QD + h * DH + j]      * rk * knw[h * DH + j];
        const float x2 = rowp[QD + h * DH + 64 + j] * rk * knw[h * DH + 64 + j];
        kb[((long)h * S_LEN + s) * DH + j]      = f2bf(x1 * cs - x2 * sn);
        kb[((long)h * S_LEN + s) * DH + 64 + j] = f2bf(x2 * cs + x1 * sn);
    }
    // V -> tiled-transposed: vt2[kh][s/32][d][s%32]
    for (int u = tid; u < KD; u += 256) {
        const int hh = u >> 7, d = u & 127;
        vt2[(((long)hh * (S_LEN / 32) + (s >> 5)) * DH + d) * 32 + (s & 31)] =
            f2bf(rowp[QD + KD + u]);
    }
}

// ---------------- flash attention: 4 waves / block, shared K/V LDS staging ----------------
// Wave w owns q-rows [qbase + w*32, +32); all 4 waves share double-buffered K/V tiles
// staged coalesced via global_load_lds with pre-swizzled source. Swapped-operand MFMA
// keeps softmax lane-local (q = lane&31); no inter-wave data exchange, 1 barrier/tile.
__global__ __launch_bounds__(256) void attn_fwd(
    const unsigned short* __restrict__ qb,   // [NH][S][DH]
    const unsigned short* __restrict__ kb,   // [NKH][S][DH]
    const unsigned short* __restrict__ vt2,  // [NKH][S/32][DH][32]
    unsigned short* __restrict__ attnb)      // [S][QD]
{
    __shared__ __align__(16) unsigned char sK[2][8192];  // [32 s][16 chunks of 16B], chunk^ (row&15)
    __shared__ __align__(16) unsigned char sV[2][8192];  // [128 d][4 chunks of 16B], chunk^((row>>1)&3)

    const int qbase = S_LEN - 128 - blockIdx.x * 128;    // longest blocks first
    const int h     = blockIdx.y;
    const int kh    = h / NG;
    const int tid   = threadIdx.x;
    const int w     = tid >> 6;
    const int lane  = tid & 63;
    const int lq    = lane & 31;
    const int hi    = lane >> 5;
    const int hi8   = hi * 8;
    const int hi4   = hi * 4;

    const int q0 = qbase + w * 32;
    const int dt = q0 >> 5;              // this wave's diagonal tile
    const int NT = (qbase >> 5) + 4;     // tiles this block stages

    // staging geometry (256 threads): K row=(tid>>4)+16j chunk=tid&15; V row=(tid>>2)+64j chunk=tid&3
    const int ksrc_off = ((tid & 15) ^ (tid >> 4)) << 4;
    const int vsrc_off = ((tid & 3) ^ ((tid >> 3) & 3)) << 4;
    const unsigned char* kgb = (const unsigned char*)(kb + (long)kh * S_LEN * DH);
    const unsigned char* vgb = (const unsigned char*)vt2 + (long)kh * (S_LEN / 32) * 8192;

    const float scale = 0.08838834764831845f;
    const float RTHR  = 8.0f / 0.08838834764831845f;

    // Q fragments (B-operand): Q[q0+lq][c*16 + hi*8 + e]
    bf16x8 qf[8];
    const unsigned short* qrow = qb + ((long)h * S_LEN + q0 + lq) * DH;
    #pragma unroll
    for (int c = 0; c < 8; ++c)
        qf[c] = *(const bf16x8*)(qrow + c * 16 + hi8);

    f32x16 o[4] = {};
    float m = -3e38f;
    float l = 0.f;

    // prologue: stage tile 0 into buf 0
    {
        const unsigned char* ks = kgb;
        const unsigned char* vs = vgb;
        #pragma unroll
        for (int j = 0; j < 2; ++j) {
            __builtin_amdgcn_global_load_lds(AS1(ks + ((tid >> 4) + 16 * j) * 256 + ksrc_off),
                                             AS3(&sK[0][0] + w * 1024 + j * 4096), 16, 0, 0);
            __builtin_amdgcn_global_load_lds(AS1(vs + ((tid >> 2) + 64 * j) * 64 + vsrc_off),
                                             AS3(&sV[0][0] + w * 1024 + j * 4096), 16, 0, 0);
        }
    }

    for (int t = 0; t < NT; ++t) {
        __syncthreads();   // drains vmcnt: buf[t&1] ready; separates reads/writes of buf[(t+1)&1]

        if (t + 1 < NT) {
            const int b = (t + 1) & 1;
            const unsigned char* ks = kgb + (long)(t + 1) * 8192;
            const unsigned char* vs = vgb + (long)(t + 1) * 8192;
            #pragma unroll
            for (int j = 0; j < 2; ++j) {
                __builtin_amdgcn_global_load_lds(AS1(ks + ((tid >> 4) + 16 * j) * 256 + ksrc_off),
                                                 AS3(&sK[b][0] + w * 1024 + j * 4096), 16, 0, 0);
                __builtin_amdgcn_global_load_lds(AS1(vs + ((tid >> 2) + 64 * j) * 64 + vsrc_off),
                                                 AS3(&sV[b][0] + w * 1024 + j * 4096), 16, 0, 0);
            }
        }

        if (t <= dt) {
            const unsigned char* sKb = sK[t & 1];
            const unsigned char* sVb = sV[t & 1];

            // ---- QK^T (swapped): sc[col=q][reg-row=k] ----
            bf16x8 kf[8];
            #pragma unroll
            for (int c = 0; c < 8; ++c)
                kf[c] = *(const bf16x8*)(sKb + lq * 256 + (((2 * c + hi) ^ (lq & 15)) << 4));
            f32x16 sc = {};
            #pragma unroll
            for (int c = 0; c < 8; ++c)
                sc = __builtin_amdgcn_mfma_f32_32x32x16_bf16(kf[c], qf[c], sc, 0, 0, 0);

            // ---- mask (diagonal tile only) ----
            float s[16];
            if (t == dt) {
                #pragma unroll
                for (int r = 0; r < 16; ++r) {
                    const int kr = (r & 3) + 8 * (r >> 2) + hi4;
                    s[r] = (kr > lq) ? -3e38f : sc[r];
                }
            } else {
                #pragma unroll
                for (int r = 0; r < 16; ++r) s[r] = sc[r];
            }

            // ---- online softmax, lane-local ----
            float mx = s[0];
            #pragma unroll
            for (int r = 1; r < 16; ++r) mx = fmaxf(mx, s[r]);
            mx = fmaxf(mx, __shfl_xor(mx, 32));

            if (!__all(mx <= m + RTHR)) {
                const float nm  = fmaxf(m, mx);
                const float fac = __expf((m - nm) * scale);
                l *= fac;
                #pragma unroll
                for (int d0 = 0; d0 < 4; ++d0)
                    #pragma unroll
                    for (int r = 0; r < 16; ++r) o[d0][r] *= fac;
                m = nm;
            }

            float p[16];
            float ps = 0.f;
            #pragma unroll
            for (int r = 0; r < 16; ++r) {
                p[r] = __expf((s[r] - m) * scale);
                ps += p[r];
            }
            ps += __shfl_xor(ps, 32);
            l += ps;

            // ---- P -> PV B-fragments via pack + half-swap ----
            unsigned pa01 = pkbf(p[0],  p[1]),  pa23 = pkbf(p[2],  p[3]);
            unsigned pb01 = pkbf(p[4],  p[5]),  pb23 = pkbf(p[6],  p[7]);
            unsigned pc01 = pkbf(p[8],  p[9]),  pc23 = pkbf(p[10], p[11]);
            unsigned pd01 = pkbf(p[12], p[13]), pd23 = pkbf(p[14], p[15]);
            unsigned xa01 = __shfl_xor((int)pa01, 32), xa23 = __shfl_xor((int)pa23, 32);
            unsigned xb01 = __shfl_xor((int)pb01, 32), xb23 = __shfl_xor((int)pb23, 32);
            unsigned xc01 = __shfl_xor((int)pc01, 32), xc23 = __shfl_xor((int)pc23, 32);
            unsigned xd01 = __shfl_xor((int)pd01, 32), xd23 = __shfl_xor((int)pd23, 32);

            union { unsigned u[4]; bf16x8 v; } pf0, pf1;
            pf0.u[0] = hi ? xb01 : pa01;
            pf0.u[1] = hi ? xb23 : pa23;
            pf0.u[2] = hi ? pb01 : xa01;
            pf0.u[3] = hi ? pb23 : xa23;
            pf1.u[0] = hi ? xd01 : pc01;
            pf1.u[1] = hi ? xd23 : pc23;
            pf1.u[2] = hi ? pd01 : xc01;
            pf1.u[3] = hi ? pd23 : xc23;

            // ---- PV (swapped): o[col=q][reg-row=d], V from LDS ----
            #pragma unroll
            for (int d0 = 0; d0 < 4; ++d0) {
                const int row = d0 * 32 + lq;
                const int sw  = (lq >> 1) & 3;
                bf16x8 vf0 = *(const bf16x8*)(sVb + row * 64 + ((hi ^ sw) << 4));
                bf16x8 vf1 = *(const bf16x8*)(sVb + row * 64 + (((2 + hi) ^ sw) << 4));
                o[d0] = __builtin_amdgcn_mfma_f32_32x32x16_bf16(vf0, pf0.v, o[d0], 0, 0, 0);
                o[d0] = __builtin_amdgcn_mfma_f32_32x32x16_bf16(vf1, pf1.v, o[d0], 0, 0, 0);
            }
        }
    }

    // ---- epilogue: out[q0+lq][h*DH + d], d = d0*32 + 8g + hi4 + 0..3 ----
    const float rl = 1.0f / l;
    unsigned short* orow = attnb + (long)(q0 + lq) * QD + h * DH;
    #pragma unroll
    for (int d0 = 0; d0 < 4; ++d0) {
        #pragma unroll
        for (int g = 0; g < 4; ++g) {
            ushort4 s4;
            s4.x = f2bf(o[d0][4 * g + 0] * rl);
            s4.y = f2bf(o[d0][4 * g + 1] * rl);
            s4.z = f2bf(o[d0][4 * g + 2] * rl);
            s4.w = f2bf(o[d0][4 * g + 3] * rl);
            *(ushort4*)(orow + d0 * 32 + 8 * g + hi4) = s4;
        }
    }
}

// ---------------- launch ----------------
extern "C" void kernel_launch(void* const* d_in, const int* in_sizes, int n_in,
                              void* d_out, int out_size, void* d_ws, size_t ws_size,
                              hipStream_t stream) {
    const int*   positions = (const int*)d_in[0];
    const float* hidden    = (const float*)d_in[1];
    const float* qkv_w     = (const float*)d_in[2];
    const float* qkv_b     = (const float*)d_in[3];
    const float* qnw       = (const float*)d_in[4];
    const float* knw       = (const float*)d_in[5];
    const float* o_w       = (const float*)d_in[6];
    float* out = (float*)d_out;

    unsigned char* ws = (unsigned char*)d_ws;
    unsigned short* hb    = (unsigned short*)(ws);               // 14,680,064 B
    unsigned short* w1    = (unsigned short*)(ws + 14680064);    // 33,030,144 B
    float*          qkvf  = (float*)(ws + 47710208);             // 37,748,736 B
    unsigned short* qbuf  = (unsigned short*)(ws + 85458944);    // 14,680,064 B
    unsigned short* kbuf  = (unsigned short*)(ws + 100139008);   //  2,097,152 B
    unsigned short* vtb   = (unsigned short*)(ws + 102236160);   //  2,097,152 B
    unsigned short* attnb = (unsigned short*)(ws);               // reuse hb (dead after GEMM1)
    unsigned short* w2    = (unsigned short*)(ws + 14680064);    // reuse w1 (dead after GEMM1)

    cvt_f32_bf16<<<(S_LEN * HIDDEN / 4 + 255) / 256, 256, 0, stream>>>(hidden, hb, S_LEN * HIDDEN / 4);
    cvt_f32_bf16<<<(NQKV * HIDDEN / 4 + 255) / 256, 256, 0, stream>>>(qkv_w, w1, NQKV * HIDDEN / 4);
    gemm_bf16<<<dim3(NQKV / 128, S_LEN / 128), 256, 0, stream>>>(hb, w1, qkvf, qkv_b, S_LEN, NQKV, HIDDEN);
    qkv_post<<<S_LEN, 256, 0, stream>>>(qkvf, positions, qnw, knw, qbuf, kbuf, vtb);
    attn_fwd<<<dim3(S_LEN / 128, NH), 256, 0, stream>>>(qbuf, kbuf, vtb, attnb);
    cvt_f32_bf16<<<(HIDDEN * QD / 4 + 255) / 256, 256, 0, stream>>>(o_w, w2, HIDDEN * QD / 4);
    gemm_bf16<<<dim3(HIDDEN / 128, S_LEN / 128), 256, 0, stream>>>(attnb, w2, out, nullptr, S_LEN, HIDDEN, QD);
}

// Round 6
// 302.550 us; speedup vs baseline: 1.4612x; 1.0946x over previous
//
#include <hip/hip_runtime.h>
#include <hip/hip_bf16.h>
#include <stdint.h>

#define S_LEN 2048
#define HIDDEN 3584
#define NH 28
#define NKH 4
#define DH 128
#define NG 7          // NH / NKH
#define NQKV 4608     // (NH + 2*NKH) * DH
#define QD 3584       // NH*DH
#define KD 512        // NKH*DH

using bf16x8 = __attribute__((ext_vector_type(8))) __bf16;
using f32x4  = __attribute__((ext_vector_type(4))) float;
using f32x16 = __attribute__((ext_vector_type(16))) float;

#define AS3(p) ((__attribute__((address_space(3))) void*)(p))
#define AS1(p) ((const __attribute__((address_space(1))) void*)(p))

__device__ __forceinline__ unsigned short f2bf(float f) {
    unsigned u = __float_as_uint(f);
    u += 0x7FFFu + ((u >> 16) & 1u);
    return (unsigned short)(u >> 16);
}
__device__ __forceinline__ unsigned cvtpk(float a, float b) {
    unsigned r;
    asm("v_cvt_pk_bf16_f32 %0, %1, %2" : "=v"(r) : "v"(a), "v"(b));
    return r;
}

// ---------------- f32 -> bf16 convert (vectorized) ----------------
__global__ void cvt_f32_bf16(const float* __restrict__ in,
                             unsigned short* __restrict__ out, int n4) {
    int i = blockIdx.x * blockDim.x + threadIdx.x;
    if (i >= n4) return;
    float4 v = ((const float4*)in)[i];
    ushort4 o;
    o.x = f2bf(v.x); o.y = f2bf(v.y); o.z = f2bf(v.z); o.w = f2bf(v.w);
    ((ushort4*)out)[i] = o;
}

// ---------------- bf16 GEMM: C[M][N] = A[M][K] * B[N][K]^T (+bias) ----------------
__global__ __launch_bounds__(256) void gemm_bf16(
    const unsigned short* __restrict__ A,
    const unsigned short* __restrict__ B,
    float* __restrict__ C,
    const float* __restrict__ bias,
    int M, int N, int K)
{
    __shared__ __align__(16) unsigned char smem[32768];
    unsigned char* As = smem;           // 128 rows x 128B (64 bf16), swizzled
    unsigned char* Bs = smem + 16384;

    const int tid  = threadIdx.x;
    const int lane = tid & 63;
    const int w    = tid >> 6;
    const int lr   = lane & 15;
    const int lg   = lane >> 4;
    const int m0   = blockIdx.y * 128;
    const int n0   = blockIdx.x * 128;
    const int wm   = (w >> 1) * 64;
    const int wn   = (w & 1) * 64;

    f32x4 acc[4][4] = {};

    const int srow  = lane >> 3;                       // row within chunk
    const int scolb = 16 * ((lane & 7) ^ srow);        // pre-swizzled source col byte

    const int nk = K >> 6;
    for (int kt = 0; kt < nk; ++kt) {
        __syncthreads();
        const long kbyte = (long)kt * 128;
        #pragma unroll
        for (int i = 0; i < 4; ++i) {
            const int c   = w * 4 + i;
            const int row = c * 8 + srow;
            const unsigned char* srcA =
                (const unsigned char*)A + (long)(m0 + row) * (K * 2) + kbyte + scolb;
            __builtin_amdgcn_global_load_lds(AS1(srcA), AS3(As + c * 1024), 16, 0, 0);
            const unsigned char* srcB =
                (const unsigned char*)B + (long)(n0 + row) * (K * 2) + kbyte + scolb;
            __builtin_amdgcn_global_load_lds(AS1(srcB), AS3(Bs + c * 1024), 16, 0, 0);
        }
        __syncthreads();
        #pragma unroll
        for (int kk = 0; kk < 2; ++kk) {
            bf16x8 af[4], bfr[4];
            #pragma unroll
            for (int mi = 0; mi < 4; ++mi) {
                const int row  = wm + mi * 16 + lr;
                const int colb = kk * 64 + lg * 16;
                af[mi] = *(const bf16x8*)(As + row * 128 + (colb ^ ((row & 7) << 4)));
            }
            #pragma unroll
            for (int ni = 0; ni < 4; ++ni) {
                const int row  = wn + ni * 16 + lr;
                const int colb = kk * 64 + lg * 16;
                bfr[ni] = *(const bf16x8*)(Bs + row * 128 + (colb ^ ((row & 7) << 4)));
            }
            #pragma unroll
            for (int mi = 0; mi < 4; ++mi)
                #pragma unroll
                for (int ni = 0; ni < 4; ++ni)
                    acc[mi][ni] = __builtin_amdgcn_mfma_f32_16x16x32_bf16(
                        af[mi], bfr[ni], acc[mi][ni], 0, 0, 0);
        }
    }

    #pragma unroll
    for (int mi = 0; mi < 4; ++mi) {
        #pragma unroll
        for (int ni = 0; ni < 4; ++ni) {
            const int col = n0 + wn + ni * 16 + lr;
            const float bv = bias ? bias[col] : 0.0f;
            #pragma unroll
            for (int j = 0; j < 4; ++j) {
                const int rowg = m0 + wm + mi * 16 + lg * 4 + j;
                C[(long)rowg * N + col] = acc[mi][ni][j] + bv;
            }
        }
    }
}

// ---------------- QKV post: RMSNorm(q,k) + RoPE, layout shuffle ----------------
// K is pre-scaled by softmax scale (1/sqrt(D)) so attention skips the multiply.
__global__ __launch_bounds__(256) void qkv_post(
    const float* __restrict__ qkv,       // [S][NQKV]
    const int* __restrict__ positions,
    const float* __restrict__ qnw,       // [QD]
    const float* __restrict__ knw,       // [KD]
    unsigned short* __restrict__ qb,     // [NH][S][DH]
    unsigned short* __restrict__ kb,     // [NKH][S][DH]
    unsigned short* __restrict__ vt2)    // [NKH][S/32][DH][32]
{
    const int s   = blockIdx.x;
    const int tid = threadIdx.x;
    const float* rowp = qkv + (long)s * NQKV;
    __shared__ float red[256];
    __shared__ float s_rq, s_rk;

    float aq = 0.f;
    for (int i = tid; i < QD; i += 256) { float v = rowp[i]; aq += v * v; }
    red[tid] = aq; __syncthreads();
    for (int off = 128; off > 0; off >>= 1) {
        if (tid < off) red[tid] += red[tid + off];
        __syncthreads();
    }
    if (tid == 0) s_rq = rsqrtf(red[0] / (float)QD + 1e-6f);
    __syncthreads();

    float ak = 0.f;
    for (int i = tid; i < KD; i += 256) { float v = rowp[QD + i]; ak += v * v; }
    red[tid] = ak; __syncthreads();
    for (int off = 128; off > 0; off >>= 1) {
        if (tid < off) red[tid] += red[tid + off];
        __syncthreads();
    }
    if (tid == 0) s_rk = rsqrtf(red[0] / (float)KD + 1e-6f);
    __syncthreads();

    const float rq  = s_rq, rk = s_rk * 0.08838834764831845f;  // fold softmax scale into K
    const float pos = (float)positions[s];
    const float c_lnf = 0.21586735253866598f; // ln(1e6)/64

    for (int u = tid; u < NH * 64; u += 256) {
        const int h = u >> 6, j = u & 63;
        const float inv = expf(-(float)j * c_lnf);
        float sn, cs;
        sincosf(pos * inv, &sn, &cs);
        const float x1 = rowp[h * DH + j]      * rq * qnw[h * DH + j];
        const float x2 = rowp[h * DH + 64 + j] * rq * qnw[h * DH + 64 + j];
        qb[((long)h * S_LEN + s) * DH + j]      = f2bf(x1 * cs - x2 * sn);
        qb[((long)h * S_LEN + s) * DH + 64 + j] = f2bf(x2 * cs + x1 * sn);
    }
    for (int u = tid; u < NKH * 64; u += 256) {
        const int h = u >> 6, j = u & 63;
        const float inv = expf(-(float)j * c_lnf);
        float sn, cs;
        sincosf(pos * inv, &sn, &cs);
        const float x1 = rowp[QD + h * DH + j]      * rk * knw[h * DH + j];
        const float x2 = rowp[QD + h * DH + 64 + j] * rk * knw[h * DH + 64 + j];
        kb[((long)h * S_LEN + s) * DH + j]      = f2bf(x1 * cs - x2 * sn);
        kb[((long)h * S_LEN + s) * DH + 64 + j] = f2bf(x2 * cs + x1 * sn);
    }
    // V -> tiled-transposed: vt2[kh][s/32][d][s%32]
    for (int u = tid; u < KD; u += 256) {
        const int hh = u >> 7, d = u & 127;
        vt2[(((long)hh * (S_LEN / 32) + (s >> 5)) * DH + d) * 32 + (s & 31)] =
            f2bf(rowp[QD + KD + u]);
    }
}

// ---------------- flash attention: 8 waves / block, one KV group / block ----------------
// Waves 0-6 each compute one q-head of the group for the SAME 32 q-rows (identical tile
// counts -> zero skew); wave 7 only stages. K/V staged once per block, shared by 7 heads.
// Swapped-operand MFMA keeps softmax lane-local (q = lane&31).
__global__ __launch_bounds__(512) void attn_fwd(
    const unsigned short* __restrict__ qb,   // [NH][S][DH]
    const unsigned short* __restrict__ kb,   // [NKH][S][DH] (pre-scaled)
    const unsigned short* __restrict__ vt2,  // [NKH][S/32][DH][32]
    unsigned short* __restrict__ attnb)      // [S][QD]
{
    __shared__ __align__(16) unsigned char sK[2][8192];  // [32 s][16 ch 16B], ch ^ (row&15)
    __shared__ __align__(16) unsigned char sV[2][8192];  // [128 d][4 ch 16B], ch ^ ((row>>1)&3)

    const int qt   = 63 - blockIdx.x;        // big q-tiles dispatched first
    const int kh   = blockIdx.y;
    const int tid  = threadIdx.x;
    const int w    = tid >> 6;
    const int lane = tid & 63;
    const int lq   = lane & 31;
    const int hi   = lane >> 5;
    const int hi8  = hi * 8;
    const int hi4  = hi * 4;
    const int q0   = qt * 32;
    const int NT   = qt + 1;

    const unsigned char* kgb = (const unsigned char*)(kb + (long)kh * S_LEN * DH);
    const unsigned char* vgb = (const unsigned char*)vt2 + (long)kh * (S_LEN / 32) * 8192;

    // staging: threads 0-255 stage K (2x16B), threads 256-511 stage V (2x16B)
    const int ksrc_off = (((tid & 15) ^ (tid >> 4)) & 15) << 4;
    const int u        = tid & 255;
    const int vsrc_off = ((u & 3) ^ ((u >> 3) & 3)) << 4;

    const float RTHR = 8.0f;   // defer-max threshold (scale already folded into K)

    // Q fragments (B-operand): Q[q0+lq][c*16 + hi*8 + e]
    bf16x8 qf[8];
    if (w < 7) {
        const int h = kh * NG + w;
        const unsigned short* qrow = qb + ((long)h * S_LEN + q0 + lq) * DH;
        #pragma unroll
        for (int c = 0; c < 8; ++c)
            qf[c] = *(const bf16x8*)(qrow + c * 16 + hi8);
    }

    f32x16 o[4] = {};
    float m = -3e38f;
    float l = 0.f;

    // prologue: stage tile 0 into buf 0
    if (tid < 256) {
        #pragma unroll
        for (int j = 0; j < 2; ++j)
            __builtin_amdgcn_global_load_lds(AS1(kgb + ((tid >> 4) + 16 * j) * 256 + ksrc_off),
                                             AS3(&sK[0][0] + w * 1024 + j * 4096), 16, 0, 0);
    } else {
        #pragma unroll
        for (int j = 0; j < 2; ++j)
            __builtin_amdgcn_global_load_lds(AS1(vgb + ((u >> 2) + 64 * j) * 64 + vsrc_off),
                                             AS3(&sV[0][0] + (w - 4) * 1024 + j * 4096), 16, 0, 0);
    }

    for (int t = 0; t < NT; ++t) {
        __syncthreads();   // drains vmcnt: buf[t&1] ready

        if (t + 1 < NT) {
            const int b = (t + 1) & 1;
            if (tid < 256) {
                const unsigned char* ks = kgb + (long)(t + 1) * 8192;
                #pragma unroll
                for (int j = 0; j < 2; ++j)
                    __builtin_amdgcn_global_load_lds(AS1(ks + ((tid >> 4) + 16 * j) * 256 + ksrc_off),
                                                     AS3(&sK[b][0] + w * 1024 + j * 4096), 16, 0, 0);
            } else {
                const unsigned char* vs = vgb + (long)(t + 1) * 8192;
                #pragma unroll
                for (int j = 0; j < 2; ++j)
                    __builtin_amdgcn_global_load_lds(AS1(vs + ((u >> 2) + 64 * j) * 64 + vsrc_off),
                                                     AS3(&sV[b][0] + (w - 4) * 1024 + j * 4096), 16, 0, 0);
            }
        }

        if (w < 7) {
            const unsigned char* sKb = sK[t & 1];
            const unsigned char* sVb = sV[t & 1];

            // ---- QK^T (swapped): sc[col=q][reg-row=k] ----
            bf16x8 kf[8];
            #pragma unroll
            for (int c = 0; c < 8; ++c)
                kf[c] = *(const bf16x8*)(sKb + lq * 256 + (((2 * c + hi) ^ (lq & 15)) << 4));
            f32x16 sc = {};
            #pragma unroll
            for (int c = 0; c < 8; ++c)
                sc = __builtin_amdgcn_mfma_f32_32x32x16_bf16(kf[c], qf[c], sc, 0, 0, 0);

            // ---- mask (diagonal tile only) ----
            float s[16];
            if (t == NT - 1) {
                #pragma unroll
                for (int r = 0; r < 16; ++r) {
                    const int kr = (r & 3) + 8 * (r >> 2) + hi4;
                    s[r] = (kr > lq) ? -3e38f : sc[r];
                }
            } else {
                #pragma unroll
                for (int r = 0; r < 16; ++r) s[r] = sc[r];
            }

            // ---- online softmax, lane-local ----
            float mx = s[0];
            #pragma unroll
            for (int r = 1; r < 16; ++r) mx = fmaxf(mx, s[r]);
            mx = fmaxf(mx, __shfl_xor(mx, 32));

            if (!__all(mx <= m + RTHR)) {
                const float nm  = fmaxf(m, mx);
                const float fac = __expf(m - nm);
                l *= fac;
                #pragma unroll
                for (int d0 = 0; d0 < 4; ++d0)
                    #pragma unroll
                    for (int r = 0; r < 16; ++r) o[d0][r] *= fac;
                m = nm;
            }

            float p[16];
            float ps = 0.f;
            #pragma unroll
            for (int r = 0; r < 16; ++r) {
                p[r] = __expf(s[r] - m);
                ps += p[r];
            }
            ps += __shfl_xor(ps, 32);
            l += ps;

            // ---- P -> PV B-fragments: cvt_pk pack + half-swap ----
            unsigned pa01 = cvtpk(p[0],  p[1]),  pa23 = cvtpk(p[2],  p[3]);
            unsigned pb01 = cvtpk(p[4],  p[5]),  pb23 = cvtpk(p[6],  p[7]);
            unsigned pc01 = cvtpk(p[8],  p[9]),  pc23 = cvtpk(p[10], p[11]);
            unsigned pd01 = cvtpk(p[12], p[13]), pd23 = cvtpk(p[14], p[15]);
            unsigned xa01 = __shfl_xor((int)pa01, 32), xa23 = __shfl_xor((int)pa23, 32);
            unsigned xb01 = __shfl_xor((int)pb01, 32), xb23 = __shfl_xor((int)pb23, 32);
            unsigned xc01 = __shfl_xor((int)pc01, 32), xc23 = __shfl_xor((int)pc23, 32);
            unsigned xd01 = __shfl_xor((int)pd01, 32), xd23 = __shfl_xor((int)pd23, 32);

            union { unsigned uu[4]; bf16x8 v; } pf0, pf1;
            pf0.uu[0] = hi ? xb01 : pa01;
            pf0.uu[1] = hi ? xb23 : pa23;
            pf0.uu[2] = hi ? pb01 : xa01;
            pf0.uu[3] = hi ? pb23 : xa23;
            pf1.uu[0] = hi ? xd01 : pc01;
            pf1.uu[1] = hi ? xd23 : pc23;
            pf1.uu[2] = hi ? pd01 : xc01;
            pf1.uu[3] = hi ? pd23 : xc23;

            // ---- PV (swapped): o[col=q][reg-row=d], V from LDS ----
            #pragma unroll
            for (int d0 = 0; d0 < 4; ++d0) {
                const int row = d0 * 32 + lq;
                const int sw  = (lq >> 1) & 3;
                bf16x8 vf0 = *(const bf16x8*)(sVb + row * 64 + ((hi ^ sw) << 4));
                bf16x8 vf1 = *(const bf16x8*)(sVb + row * 64 + (((2 + hi) ^ sw) << 4));
                o[d0] = __builtin_amdgcn_mfma_f32_32x32x16_bf16(vf0, pf0.v, o[d0], 0, 0, 0);
                o[d0] = __builtin_amdgcn_mfma_f32_32x32x16_bf16(vf1, pf1.v, o[d0], 0, 0, 0);
            }
        }
    }

    if (w == 7) return;

    // ---- epilogue: out[q0+lq][h*DH + d], d = d0*32 + 8g + hi4 + 0..3 ----
    const float rl = 1.0f / l;
    unsigned short* orow = attnb + (long)(q0 + lq) * QD + (kh * NG + w) * DH;
    #pragma unroll
    for (int d0 = 0; d0 < 4; ++d0) {
        #pragma unroll
        for (int g = 0; g < 4; ++g) {
            ushort4 s4;
            s4.x = f2bf(o[d0][4 * g + 0] * rl);
            s4.y = f2bf(o[d0][4 * g + 1] * rl);
            s4.z = f2bf(o[d0][4 * g + 2] * rl);
            s4.w = f2bf(o[d0][4 * g + 3] * rl);
            *(ushort4*)(orow + d0 * 32 + 8 * g + hi4) = s4;
        }
    }
}

// ---------------- launch ----------------
extern "C" void kernel_launch(void* const* d_in, const int* in_sizes, int n_in,
                              void* d_out, int out_size, void* d_ws, size_t ws_size,
                              hipStream_t stream) {
    const int*   positions = (const int*)d_in[0];
    const float* hidden    = (const float*)d_in[1];
    const float* qkv_w     = (const float*)d_in[2];
    const float* qkv_b     = (const float*)d_in[3];
    const float* qnw       = (const float*)d_in[4];
    const float* knw       = (const float*)d_in[5];
    const float* o_w       = (const float*)d_in[6];
    float* out = (float*)d_out;

    unsigned char* ws = (unsigned char*)d_ws;
    unsigned short* hb    = (unsigned short*)(ws);               // 14,680,064 B
    unsigned short* w1    = (unsigned short*)(ws + 14680064);    // 33,030,144 B
    float*          qkvf  = (float*)(ws + 47710208);             // 37,748,736 B
    unsigned short* qbuf  = (unsigned short*)(ws + 85458944);    // 14,680,064 B
    unsigned short* kbuf  = (unsigned short*)(ws + 100139008);   //  2,097,152 B
    unsigned short* vtb   = (unsigned short*)(ws + 102236160);   //  2,097,152 B
    unsigned short* attnb = (unsigned short*)(ws);               // reuse hb (dead after GEMM1)
    unsigned short* w2    = (unsigned short*)(ws + 14680064);    // reuse w1 (dead after GEMM1)

    cvt_f32_bf16<<<(S_LEN * HIDDEN / 4 + 255) / 256, 256, 0, stream>>>(hidden, hb, S_LEN * HIDDEN / 4);
    cvt_f32_bf16<<<(NQKV * HIDDEN / 4 + 255) / 256, 256, 0, stream>>>(qkv_w, w1, NQKV * HIDDEN / 4);
    gemm_bf16<<<dim3(NQKV / 128, S_LEN / 128), 256, 0, stream>>>(hb, w1, qkvf, qkv_b, S_LEN, NQKV, HIDDEN);
    qkv_post<<<S_LEN, 256, 0, stream>>>(qkvf, positions, qnw, knw, qbuf, kbuf, vtb);
    attn_fwd<<<dim3(S_LEN / 32, NKH), 512, 0, stream>>>(qbuf, kbuf, vtb, attnb);
    cvt_f32_bf16<<<(HIDDEN * QD / 4 + 255) / 256, 256, 0, stream>>>(o_w, w2, HIDDEN * QD / 4);
    gemm_bf16<<<dim3(HIDDEN / 128, S_LEN / 128), 256, 0, stream>>>(attnb, w2, out, nullptr, S_LEN, HIDDEN, QD);
}

// Round 7
// 291.938 us; speedup vs baseline: 1.5143x; 1.0363x over previous
//
#include <hip/hip_runtime.h>
#include <hip/hip_bf16.h>
#include <stdint.h>

#define S_LEN 2048
#define HIDDEN 3584
#define NH 28
#define NKH 4
#define DH 128
#define NG 7          // NH / NKH
#define NQKV 4608     // (NH + 2*NKH) * DH
#define QD 3584       // NH*DH
#define KD 512        // NKH*DH

using bf16x8 = __attribute__((ext_vector_type(8))) __bf16;
using f32x4  = __attribute__((ext_vector_type(4))) float;
using f32x16 = __attribute__((ext_vector_type(16))) float;

#define AS3(p) ((__attribute__((address_space(3))) void*)(p))
#define AS1(p) ((const __attribute__((address_space(1))) void*)(p))

__device__ __forceinline__ unsigned short f2bf(float f) {
    unsigned u = __float_as_uint(f);
    u += 0x7FFFu + ((u >> 16) & 1u);
    return (unsigned short)(u >> 16);
}
__device__ __forceinline__ unsigned cvtpk(float a, float b) {
    unsigned r;
    asm("v_cvt_pk_bf16_f32 %0, %1, %2" : "=v"(r) : "v"(a), "v"(b));
    return r;
}

// ---------------- f32 -> bf16 convert (two tensors fused) ----------------
__global__ void cvt2_f32_bf16(const float* __restrict__ a, unsigned short* __restrict__ oa, int na4,
                              const float* __restrict__ b, unsigned short* __restrict__ ob, int nb4) {
    int i = blockIdx.x * blockDim.x + threadIdx.x;
    const float* src;
    unsigned short* dst;
    int n;
    if (i < na4)            { src = a; dst = oa; n = i; }
    else if (i < na4 + nb4) { src = b; dst = ob; n = i - na4; }
    else return;
    float4 v = ((const float4*)src)[n];
    ushort4 o;
    o.x = f2bf(v.x); o.y = f2bf(v.y); o.z = f2bf(v.z); o.w = f2bf(v.w);
    ((ushort4*)dst)[n] = o;
}

__global__ void cvt_f32_bf16(const float* __restrict__ in,
                             unsigned short* __restrict__ out, int n4) {
    int i = blockIdx.x * blockDim.x + threadIdx.x;
    if (i >= n4) return;
    float4 v = ((const float4*)in)[i];
    ushort4 o;
    o.x = f2bf(v.x); o.y = f2bf(v.y); o.z = f2bf(v.z); o.w = f2bf(v.w);
    ((ushort4*)out)[i] = o;
}

// ---------------- bf16 GEMM: C[M][N] = A[M][K] * B[N][K]^T (+bias) ----------------
// 128x128 tile, BK=64, 4 waves. Double-buffered LDS; stage(t+1) issued BEFORE compute(t),
// drained by a single vmcnt(0)+s_barrier at iteration end (T3-minimum schedule): the
// prefetch has one full compute phase to fly instead of being barrier-exposed.
__global__ __launch_bounds__(256) void gemm_bf16(
    const unsigned short* __restrict__ A,
    const unsigned short* __restrict__ B,
    float* __restrict__ C,
    const float* __restrict__ bias,
    int M, int N, int K)
{
    __shared__ __align__(16) unsigned char smem[2][32768];

    const int tid  = threadIdx.x;
    const int lane = tid & 63;
    const int w    = tid >> 6;
    const int lr   = lane & 15;
    const int lg   = lane >> 4;
    const int m0   = blockIdx.y * 128;
    const int n0   = blockIdx.x * 128;
    const int wm   = (w >> 1) * 64;
    const int wn   = (w & 1) * 64;

    f32x4 acc[4][4] = {};

    const int srow  = lane >> 3;                       // row within chunk
    const int scolb = 16 * ((lane & 7) ^ srow);        // pre-swizzled source col byte
    const unsigned char* Ab = (const unsigned char*)A;
    const unsigned char* Bb = (const unsigned char*)B;

    // stage tile kt into buffer b: A -> smem[b][0..16K), B -> smem[b][16K..32K)
    auto stage = [&](int kt, int b) {
        const long kbyte = (long)kt * 128;
        #pragma unroll
        for (int i = 0; i < 4; ++i) {
            const int c   = w * 4 + i;
            const int row = c * 8 + srow;
            __builtin_amdgcn_global_load_lds(
                AS1(Ab + (long)(m0 + row) * (K * 2) + kbyte + scolb),
                AS3(&smem[b][0] + c * 1024), 16, 0, 0);
            __builtin_amdgcn_global_load_lds(
                AS1(Bb + (long)(n0 + row) * (K * 2) + kbyte + scolb),
                AS3(&smem[b][16384] + c * 1024), 16, 0, 0);
        }
    };

    stage(0, 0);
    asm volatile("s_waitcnt vmcnt(0)" ::: "memory");
    __builtin_amdgcn_s_barrier();

    const int nk = K >> 6;
    for (int kt = 0; kt < nk; ++kt) {
        const int cur = kt & 1;
        if (kt + 1 < nk) stage(kt + 1, cur ^ 1);

        const unsigned char* As = &smem[cur][0];
        const unsigned char* Bs = &smem[cur][16384];
        #pragma unroll
        for (int kk = 0; kk < 2; ++kk) {
            bf16x8 af[4], bfr[4];
            #pragma unroll
            for (int mi = 0; mi < 4; ++mi) {
                const int row  = wm + mi * 16 + lr;
                const int colb = kk * 64 + lg * 16;
                af[mi] = *(const bf16x8*)(As + row * 128 + (colb ^ ((row & 7) << 4)));
            }
            #pragma unroll
            for (int ni = 0; ni < 4; ++ni) {
                const int row  = wn + ni * 16 + lr;
                const int colb = kk * 64 + lg * 16;
                bfr[ni] = *(const bf16x8*)(Bs + row * 128 + (colb ^ ((row & 7) << 4)));
            }
            #pragma unroll
            for (int mi = 0; mi < 4; ++mi)
                #pragma unroll
                for (int ni = 0; ni < 4; ++ni)
                    acc[mi][ni] = __builtin_amdgcn_mfma_f32_16x16x32_bf16(
                        af[mi], bfr[ni], acc[mi][ni], 0, 0, 0);
        }

        asm volatile("s_waitcnt vmcnt(0)" ::: "memory");
        __builtin_amdgcn_s_barrier();
    }

    #pragma unroll
    for (int mi = 0; mi < 4; ++mi) {
        #pragma unroll
        for (int ni = 0; ni < 4; ++ni) {
            const int col = n0 + wn + ni * 16 + lr;
            const float bv = bias ? bias[col] : 0.0f;
            #pragma unroll
            for (int j = 0; j < 4; ++j) {
                const int rowg = m0 + wm + mi * 16 + lg * 4 + j;
                C[(long)rowg * N + col] = acc[mi][ni][j] + bv;
            }
        }
    }
}

// ---------------- QKV post: RMSNorm(q,k) + RoPE, layout shuffle ----------------
// K is pre-scaled by softmax scale (1/sqrt(D)) so attention skips the multiply.
__global__ __launch_bounds__(256) void qkv_post(
    const float* __restrict__ qkv,       // [S][NQKV]
    const int* __restrict__ positions,
    const float* __restrict__ qnw,       // [QD]
    const float* __restrict__ knw,       // [KD]
    unsigned short* __restrict__ qb,     // [NH][S][DH]
    unsigned short* __restrict__ kb,     // [NKH][S][DH]
    unsigned short* __restrict__ vt2)    // [NKH][S/32][DH][32]
{
    const int s   = blockIdx.x;
    const int tid = threadIdx.x;
    const float* rowp = qkv + (long)s * NQKV;
    __shared__ float red[256];
    __shared__ float s_rq, s_rk;

    float aq = 0.f;
    for (int i = tid; i < QD; i += 256) { float v = rowp[i]; aq += v * v; }
    red[tid] = aq; __syncthreads();
    for (int off = 128; off > 0; off >>= 1) {
        if (tid < off) red[tid] += red[tid + off];
        __syncthreads();
    }
    if (tid == 0) s_rq = rsqrtf(red[0] / (float)QD + 1e-6f);
    __syncthreads();

    float ak = 0.f;
    for (int i = tid; i < KD; i += 256) { float v = rowp[QD + i]; ak += v * v; }
    red[tid] = ak; __syncthreads();
    for (int off = 128; off > 0; off >>= 1) {
        if (tid < off) red[tid] += red[tid + off];
        __syncthreads();
    }
    if (tid == 0) s_rk = rsqrtf(red[0] / (float)KD + 1e-6f);
    __syncthreads();

    const float rq  = s_rq, rk = s_rk * 0.08838834764831845f;  // fold softmax scale into K
    const float pos = (float)positions[s];
    const float c_lnf = 0.21586735253866598f; // ln(1e6)/64

    for (int u = tid; u < NH * 64; u += 256) {
        const int h = u >> 6, j = u & 63;
        const float inv = expf(-(float)j * c_lnf);
        float sn, cs;
        sincosf(pos * inv, &sn, &cs);
        const float x1 = rowp[h * DH + j]      * rq * qnw[h * DH + j];
        const float x2 = rowp[h * DH + 64 + j] * rq * qnw[h * DH + 64 + j];
        qb[((long)h * S_LEN + s) * DH + j]      = f2bf(x1 * cs - x2 * sn);
        qb[((long)h * S_LEN + s) * DH + 64 + j] = f2bf(x2 * cs + x1 * sn);
    }
    for (int u = tid; u < NKH * 64; u += 256) {
        const int h = u >> 6, j = u & 63;
        const float inv = expf(-(float)j * c_lnf);
        float sn, cs;
        sincosf(pos * inv, &sn, &cs);
        const float x1 = rowp[QD + h * DH + j]      * rk * knw[h * DH + j];
        const float x2 = rowp[QD + h * DH + 64 + j] * rk * knw[h * DH + 64 + j];
        kb[((long)h * S_LEN + s) * DH + j]      = f2bf(x1 * cs - x2 * sn);
        kb[((long)h * S_LEN + s) * DH + 64 + j] = f2bf(x2 * cs + x1 * sn);
    }
    // V -> tiled-transposed: vt2[kh][s/32][d][s%32]
    for (int u = tid; u < KD; u += 256) {
        const int hh = u >> 7, d = u & 127;
        vt2[(((long)hh * (S_LEN / 32) + (s >> 5)) * DH + d) * 32 + (s & 31)] =
            f2bf(rowp[QD + KD + u]);
    }
}

// ---------------- flash attention: 8 waves / block, one KV group / block ----------------
__global__ __launch_bounds__(512) void attn_fwd(
    const unsigned short* __restrict__ qb,   // [NH][S][DH]
    const unsigned short* __restrict__ kb,   // [NKH][S][DH] (pre-scaled)
    const unsigned short* __restrict__ vt2,  // [NKH][S/32][DH][32]
    unsigned short* __restrict__ attnb)      // [S][QD]
{
    __shared__ __align__(16) unsigned char sK[2][8192];  // [32 s][16 ch 16B], ch ^ (row&15)
    __shared__ __align__(16) unsigned char sV[2][8192];  // [128 d][4 ch 16B], ch ^ ((row>>1)&3)

    const int qt   = 63 - blockIdx.x;        // big q-tiles dispatched first
    const int kh   = blockIdx.y;
    const int tid  = threadIdx.x;
    const int w    = tid >> 6;
    const int lane = tid & 63;
    const int lq   = lane & 31;
    const int hi   = lane >> 5;
    const int hi8  = hi * 8;
    const int hi4  = hi * 4;
    const int q0   = qt * 32;
    const int NT   = qt + 1;

    const unsigned char* kgb = (const unsigned char*)(kb + (long)kh * S_LEN * DH);
    const unsigned char* vgb = (const unsigned char*)vt2 + (long)kh * (S_LEN / 32) * 8192;

    // staging: threads 0-255 stage K (2x16B), threads 256-511 stage V (2x16B)
    const int ksrc_off = (((tid & 15) ^ (tid >> 4)) & 15) << 4;
    const int u        = tid & 255;
    const int vsrc_off = ((u & 3) ^ ((u >> 3) & 3)) << 4;

    const float RTHR = 8.0f;   // defer-max threshold (scale already folded into K)

    // Q fragments (B-operand): Q[q0+lq][c*16 + hi*8 + e]
    bf16x8 qf[8];
    if (w < 7) {
        const int h = kh * NG + w;
        const unsigned short* qrow = qb + ((long)h * S_LEN + q0 + lq) * DH;
        #pragma unroll
        for (int c = 0; c < 8; ++c)
            qf[c] = *(const bf16x8*)(qrow + c * 16 + hi8);
    }

    f32x16 o[4] = {};
    float m = -3e38f;
    float l = 0.f;

    // prologue: stage tile 0 into buf 0
    if (tid < 256) {
        #pragma unroll
        for (int j = 0; j < 2; ++j)
            __builtin_amdgcn_global_load_lds(AS1(kgb + ((tid >> 4) + 16 * j) * 256 + ksrc_off),
                                             AS3(&sK[0][0] + w * 1024 + j * 4096), 16, 0, 0);
    } else {
        #pragma unroll
        for (int j = 0; j < 2; ++j)
            __builtin_amdgcn_global_load_lds(AS1(vgb + ((u >> 2) + 64 * j) * 64 + vsrc_off),
                                             AS3(&sV[0][0] + (w - 4) * 1024 + j * 4096), 16, 0, 0);
    }

    for (int t = 0; t < NT; ++t) {
        __syncthreads();   // drains vmcnt: buf[t&1] ready

        if (t + 1 < NT) {
            const int b = (t + 1) & 1;
            if (tid < 256) {
                const unsigned char* ks = kgb + (long)(t + 1) * 8192;
                #pragma unroll
                for (int j = 0; j < 2; ++j)
                    __builtin_amdgcn_global_load_lds(AS1(ks + ((tid >> 4) + 16 * j) * 256 + ksrc_off),
                                                     AS3(&sK[b][0] + w * 1024 + j * 4096), 16, 0, 0);
            } else {
                const unsigned char* vs = vgb + (long)(t + 1) * 8192;
                #pragma unroll
                for (int j = 0; j < 2; ++j)
                    __builtin_amdgcn_global_load_lds(AS1(vs + ((u >> 2) + 64 * j) * 64 + vsrc_off),
                                                     AS3(&sV[b][0] + (w - 4) * 1024 + j * 4096), 16, 0, 0);
            }
        }

        if (w < 7) {
            const unsigned char* sKb = sK[t & 1];
            const unsigned char* sVb = sV[t & 1];

            // ---- QK^T (swapped): sc[col=q][reg-row=k] ----
            bf16x8 kf[8];
            #pragma unroll
            for (int c = 0; c < 8; ++c)
                kf[c] = *(const bf16x8*)(sKb + lq * 256 + (((2 * c + hi) ^ (lq & 15)) << 4));
            f32x16 sc = {};
            #pragma unroll
            for (int c = 0; c < 8; ++c)
                sc = __builtin_amdgcn_mfma_f32_32x32x16_bf16(kf[c], qf[c], sc, 0, 0, 0);

            // ---- mask (diagonal tile only) ----
            float s[16];
            if (t == NT - 1) {
                #pragma unroll
                for (int r = 0; r < 16; ++r) {
                    const int kr = (r & 3) + 8 * (r >> 2) + hi4;
                    s[r] = (kr > lq) ? -3e38f : sc[r];
                }
            } else {
                #pragma unroll
                for (int r = 0; r < 16; ++r) s[r] = sc[r];
            }

            // ---- online softmax, lane-local ----
            float mx = s[0];
            #pragma unroll
            for (int r = 1; r < 16; ++r) mx = fmaxf(mx, s[r]);
            mx = fmaxf(mx, __shfl_xor(mx, 32));

            if (!__all(mx <= m + RTHR)) {
                const float nm  = fmaxf(m, mx);
                const float fac = __expf(m - nm);
                l *= fac;
                #pragma unroll
                for (int d0 = 0; d0 < 4; ++d0)
                    #pragma unroll
                    for (int r = 0; r < 16; ++r) o[d0][r] *= fac;
                m = nm;
            }

            float p[16];
            float ps = 0.f;
            #pragma unroll
            for (int r = 0; r < 16; ++r) {
                p[r] = __expf(s[r] - m);
                ps += p[r];
            }
            ps += __shfl_xor(ps, 32);
            l += ps;

            // ---- P -> PV B-fragments: cvt_pk pack + half-swap ----
            unsigned pa01 = cvtpk(p[0],  p[1]),  pa23 = cvtpk(p[2],  p[3]);
            unsigned pb01 = cvtpk(p[4],  p[5]),  pb23 = cvtpk(p[6],  p[7]);
            unsigned pc01 = cvtpk(p[8],  p[9]),  pc23 = cvtpk(p[10], p[11]);
            unsigned pd01 = cvtpk(p[12], p[13]), pd23 = cvtpk(p[14], p[15]);
            unsigned xa01 = __shfl_xor((int)pa01, 32), xa23 = __shfl_xor((int)pa23, 32);
            unsigned xb01 = __shfl_xor((int)pb01, 32), xb23 = __shfl_xor((int)pb23, 32);
            unsigned xc01 = __shfl_xor((int)pc01, 32), xc23 = __shfl_xor((int)pc23, 32);
            unsigned xd01 = __shfl_xor((int)pd01, 32), xd23 = __shfl_xor((int)pd23, 32);

            union { unsigned uu[4]; bf16x8 v; } pf0, pf1;
            pf0.uu[0] = hi ? xb01 : pa01;
            pf0.uu[1] = hi ? xb23 : pa23;
            pf0.uu[2] = hi ? pb01 : xa01;
            pf0.uu[3] = hi ? pb23 : xa23;
            pf1.uu[0] = hi ? xd01 : pc01;
            pf1.uu[1] = hi ? xd23 : pc23;
            pf1.uu[2] = hi ? pd01 : xc01;
            pf1.uu[3] = hi ? pd23 : xc23;

            // ---- PV (swapped): o[col=q][reg-row=d], V from LDS ----
            #pragma unroll
            for (int d0 = 0; d0 < 4; ++d0) {
                const int row = d0 * 32 + lq;
                const int sw  = (lq >> 1) & 3;
                bf16x8 vf0 = *(const bf16x8*)(sVb + row * 64 + ((hi ^ sw) << 4));
                bf16x8 vf1 = *(const bf16x8*)(sVb + row * 64 + (((2 + hi) ^ sw) << 4));
                o[d0] = __builtin_amdgcn_mfma_f32_32x32x16_bf16(vf0, pf0.v, o[d0], 0, 0, 0);
                o[d0] = __builtin_amdgcn_mfma_f32_32x32x16_bf16(vf1, pf1.v, o[d0], 0, 0, 0);
            }
        }
    }

    if (w == 7) return;

    // ---- epilogue: out[q0+lq][h*DH + d], d = d0*32 + 8g + hi4 + 0..3 ----
    const float rl = 1.0f / l;
    unsigned short* orow = attnb + (long)(q0 + lq) * QD + (kh * NG + w) * DH;
    #pragma unroll
    for (int d0 = 0; d0 < 4; ++d0) {
        #pragma unroll
        for (int g = 0; g < 4; ++g) {
            ushort4 s4;
            s4.x = f2bf(o[d0][4 * g + 0] * rl);
            s4.y = f2bf(o[d0][4 * g + 1] * rl);
            s4.z = f2bf(o[d0][4 * g + 2] * rl);
            s4.w = f2bf(o[d0][4 * g + 3] * rl);
            *(ushort4*)(orow + d0 * 32 + 8 * g + hi4) = s4;
        }
    }
}

// ---------------- launch ----------------
extern "C" void kernel_launch(void* const* d_in, const int* in_sizes, int n_in,
                              void* d_out, int out_size, void* d_ws, size_t ws_size,
                              hipStream_t stream) {
    const int*   positions = (const int*)d_in[0];
    const float* hidden    = (const float*)d_in[1];
    const float* qkv_w     = (const float*)d_in[2];
    const float* qkv_b     = (const float*)d_in[3];
    const float* qnw       = (const float*)d_in[4];
    const float* knw       = (const float*)d_in[5];
    const float* o_w       = (const float*)d_in[6];
    float* out = (float*)d_out;

    unsigned char* ws = (unsigned char*)d_ws;
    unsigned short* hb    = (unsigned short*)(ws);               // 14,680,064 B
    unsigned short* w1    = (unsigned short*)(ws + 14680064);    // 33,030,144 B
    float*          qkvf  = (float*)(ws + 47710208);             // 37,748,736 B
    unsigned short* qbuf  = (unsigned short*)(ws + 85458944);    // 14,680,064 B
    unsigned short* kbuf  = (unsigned short*)(ws + 100139008);   //  2,097,152 B
    unsigned short* vtb   = (unsigned short*)(ws + 102236160);   //  2,097,152 B
    unsigned short* attnb = (unsigned short*)(ws);               // reuse hb (dead after GEMM1)
    unsigned short* w2    = (unsigned short*)(ws + 14680064);    // reuse w1 (dead after GEMM1)

    const int na4 = S_LEN * HIDDEN / 4;
    const int nb4 = NQKV * HIDDEN / 4;
    cvt2_f32_bf16<<<(na4 + nb4 + 255) / 256, 256, 0, stream>>>(hidden, hb, na4, qkv_w, w1, nb4);
    gemm_bf16<<<dim3(NQKV / 128, S_LEN / 128), 256, 0, stream>>>(hb, w1, qkvf, qkv_b, S_LEN, NQKV, HIDDEN);
    qkv_post<<<S_LEN, 256, 0, stream>>>(qkvf, positions, qnw, knw, qbuf, kbuf, vtb);
    attn_fwd<<<dim3(S_LEN / 32, NKH), 512, 0, stream>>>(qbuf, kbuf, vtb, attnb);
    cvt_f32_bf16<<<(HIDDEN * QD / 4 + 255) / 256, 256, 0, stream>>>(o_w, w2, HIDDEN * QD / 4);
    gemm_bf16<<<dim3(HIDDEN / 128, S_LEN / 128), 256, 0, stream>>>(attnb, w2, out, nullptr, S_LEN, HIDDEN, QD);
}

// Round 8
// 290.506 us; speedup vs baseline: 1.5217x; 1.0049x over previous
//
#include <hip/hip_runtime.h>
#include <hip/hip_bf16.h>
#include <stdint.h>

#define S_LEN 2048
#define HIDDEN 3584
#define NH 28
#define NKH 4
#define DH 128
#define NG 7          // NH / NKH
#define NQKV 4608     // (NH + 2*NKH) * DH
#define QD 3584       // NH*DH
#define KD 512        // NKH*DH

using bf16x8 = __attribute__((ext_vector_type(8))) __bf16;
using f32x4  = __attribute__((ext_vector_type(4))) float;
using f32x16 = __attribute__((ext_vector_type(16))) float;

#define AS3(p) ((__attribute__((address_space(3))) void*)(p))
#define AS1(p) ((const __attribute__((address_space(1))) void*)(p))

__device__ __forceinline__ unsigned short f2bf(float f) {
    unsigned u = __float_as_uint(f);
    u += 0x7FFFu + ((u >> 16) & 1u);
    return (unsigned short)(u >> 16);
}
__device__ __forceinline__ unsigned cvtpk(float a, float b) {
    unsigned r;
    asm("v_cvt_pk_bf16_f32 %0, %1, %2" : "=v"(r) : "v"(a), "v"(b));
    return r;
}

// ---------------- f32 -> bf16 convert (two tensors fused) ----------------
__global__ void cvt2_f32_bf16(const float* __restrict__ a, unsigned short* __restrict__ oa, int na4,
                              const float* __restrict__ b, unsigned short* __restrict__ ob, int nb4) {
    int i = blockIdx.x * blockDim.x + threadIdx.x;
    const float* src;
    unsigned short* dst;
    int n;
    if (i < na4)            { src = a; dst = oa; n = i; }
    else if (i < na4 + nb4) { src = b; dst = ob; n = i - na4; }
    else return;
    float4 v = ((const float4*)src)[n];
    ushort4 o;
    o.x = f2bf(v.x); o.y = f2bf(v.y); o.z = f2bf(v.z); o.w = f2bf(v.w);
    ((ushort4*)dst)[n] = o;
}

__global__ void cvt_f32_bf16(const float* __restrict__ in,
                             unsigned short* __restrict__ out, int n4) {
    int i = blockIdx.x * blockDim.x + threadIdx.x;
    if (i >= n4) return;
    float4 v = ((const float4*)in)[i];
    ushort4 o;
    o.x = f2bf(v.x); o.y = f2bf(v.y); o.z = f2bf(v.z); o.w = f2bf(v.w);
    ((ushort4*)out)[i] = o;
}

// ---------------- bf16 GEMM: C[M][N] = A[M][K] * B[N][K]^T (+bias) ----------------
// 128x128 tile, BK=64, 4 waves, double-buffered 2-phase schedule.
// 1D grid + bijective XCD swizzle (m204): each XCD owns a contiguous band of
// N-column panels (y fastest within band) so B-panels stay L2-resident per XCD.
__global__ __launch_bounds__(256) void gemm_bf16(
    const unsigned short* __restrict__ A,
    const unsigned short* __restrict__ B,
    float* __restrict__ C,
    const float* __restrict__ bias,
    int M, int N, int K, int nby)
{
    __shared__ __align__(16) unsigned char smem[2][32768];

    const int nwg = gridDim.x;
    const int id  = blockIdx.x;
    const int qq  = nwg >> 3, rr = nwg & 7;
    const int xcd = id & 7;
    const int wg  = (xcd < rr ? xcd * (qq + 1) : rr * (qq + 1) + (xcd - rr) * qq) + (id >> 3);
    const int bx  = wg / nby;          // n-tile (B panel) — contiguous per XCD
    const int by  = wg % nby;          // m-tile, fastest -> reuse B panel

    const int tid  = threadIdx.x;
    const int lane = tid & 63;
    const int w    = tid >> 6;
    const int lr   = lane & 15;
    const int lg   = lane >> 4;
    const int m0   = by * 128;
    const int n0   = bx * 128;
    const int wm   = (w >> 1) * 64;
    const int wn   = (w & 1) * 64;

    f32x4 acc[4][4] = {};

    const int srow  = lane >> 3;                       // row within chunk
    const int scolb = 16 * ((lane & 7) ^ srow);        // pre-swizzled source col byte
    const unsigned char* Ab = (const unsigned char*)A;
    const unsigned char* Bb = (const unsigned char*)B;

    auto stage = [&](int kt, int b) {
        const long kbyte = (long)kt * 128;
        #pragma unroll
        for (int i = 0; i < 4; ++i) {
            const int c   = w * 4 + i;
            const int row = c * 8 + srow;
            __builtin_amdgcn_global_load_lds(
                AS1(Ab + (long)(m0 + row) * (K * 2) + kbyte + scolb),
                AS3(&smem[b][0] + c * 1024), 16, 0, 0);
            __builtin_amdgcn_global_load_lds(
                AS1(Bb + (long)(n0 + row) * (K * 2) + kbyte + scolb),
                AS3(&smem[b][16384] + c * 1024), 16, 0, 0);
        }
    };

    stage(0, 0);
    asm volatile("s_waitcnt vmcnt(0)" ::: "memory");
    __builtin_amdgcn_s_barrier();

    const int nk = K >> 6;
    for (int kt = 0; kt < nk; ++kt) {
        const int cur = kt & 1;
        if (kt + 1 < nk) stage(kt + 1, cur ^ 1);

        const unsigned char* As = &smem[cur][0];
        const unsigned char* Bs = &smem[cur][16384];
        #pragma unroll
        for (int kk = 0; kk < 2; ++kk) {
            bf16x8 af[4], bfr[4];
            #pragma unroll
            for (int mi = 0; mi < 4; ++mi) {
                const int row  = wm + mi * 16 + lr;
                const int colb = kk * 64 + lg * 16;
                af[mi] = *(const bf16x8*)(As + row * 128 + (colb ^ ((row & 7) << 4)));
            }
            #pragma unroll
            for (int ni = 0; ni < 4; ++ni) {
                const int row  = wn + ni * 16 + lr;
                const int colb = kk * 64 + lg * 16;
                bfr[ni] = *(const bf16x8*)(Bs + row * 128 + (colb ^ ((row & 7) << 4)));
            }
            #pragma unroll
            for (int mi = 0; mi < 4; ++mi)
                #pragma unroll
                for (int ni = 0; ni < 4; ++ni)
                    acc[mi][ni] = __builtin_amdgcn_mfma_f32_16x16x32_bf16(
                        af[mi], bfr[ni], acc[mi][ni], 0, 0, 0);
        }

        asm volatile("s_waitcnt vmcnt(0)" ::: "memory");
        __builtin_amdgcn_s_barrier();
    }

    #pragma unroll
    for (int mi = 0; mi < 4; ++mi) {
        #pragma unroll
        for (int ni = 0; ni < 4; ++ni) {
            const int col = n0 + wn + ni * 16 + lr;
            const float bv = bias ? bias[col] : 0.0f;
            #pragma unroll
            for (int j = 0; j < 4; ++j) {
                const int rowg = m0 + wm + mi * 16 + lg * 4 + j;
                C[(long)rowg * N + col] = acc[mi][ni][j] + bv;
            }
        }
    }
}

// ---------------- QKV post: RMSNorm(q,k) + RoPE, layout shuffle ----------------
// K is pre-scaled by softmax scale (1/sqrt(D)) so attention skips the multiply.
__global__ __launch_bounds__(256) void qkv_post(
    const float* __restrict__ qkv,       // [S][NQKV]
    const int* __restrict__ positions,
    const float* __restrict__ qnw,       // [QD]
    const float* __restrict__ knw,       // [KD]
    unsigned short* __restrict__ qb,     // [NH][S][DH]
    unsigned short* __restrict__ kb,     // [NKH][S][DH]
    unsigned short* __restrict__ vt2)    // [NKH][S/32][DH][32]
{
    const int s   = blockIdx.x;
    const int tid = threadIdx.x;
    const float* rowp = qkv + (long)s * NQKV;
    __shared__ float red[256];
    __shared__ float s_rq, s_rk;

    float aq = 0.f;
    for (int i = tid; i < QD; i += 256) { float v = rowp[i]; aq += v * v; }
    red[tid] = aq; __syncthreads();
    for (int off = 128; off > 0; off >>= 1) {
        if (tid < off) red[tid] += red[tid + off];
        __syncthreads();
    }
    if (tid == 0) s_rq = rsqrtf(red[0] / (float)QD + 1e-6f);
    __syncthreads();

    float ak = 0.f;
    for (int i = tid; i < KD; i += 256) { float v = rowp[QD + i]; ak += v * v; }
    red[tid] = ak; __syncthreads();
    for (int off = 128; off > 0; off >>= 1) {
        if (tid < off) red[tid] += red[tid + off];
        __syncthreads();
    }
    if (tid == 0) s_rk = rsqrtf(red[0] / (float)KD + 1e-6f);
    __syncthreads();

    const float rq  = s_rq, rk = s_rk * 0.08838834764831845f;  // fold softmax scale into K
    const float pos = (float)positions[s];
    const float c_lnf = 0.21586735253866598f; // ln(1e6)/64

    for (int u = tid; u < NH * 64; u += 256) {
        const int h = u >> 6, j = u & 63;
        const float inv = expf(-(float)j * c_lnf);
        float sn, cs;
        sincosf(pos * inv, &sn, &cs);
        const float x1 = rowp[h * DH + j]      * rq * qnw[h * DH + j];
        const float x2 = rowp[h * DH + 64 + j] * rq * qnw[h * DH + 64 + j];
        qb[((long)h * S_LEN + s) * DH + j]      = f2bf(x1 * cs - x2 * sn);
        qb[((long)h * S_LEN + s) * DH + 64 + j] = f2bf(x2 * cs + x1 * sn);
    }
    for (int u = tid; u < NKH * 64; u += 256) {
        const int h = u >> 6, j = u & 63;
        const float inv = expf(-(float)j * c_lnf);
        float sn, cs;
        sincosf(pos * inv, &sn, &cs);
        const float x1 = rowp[QD + h * DH + j]      * rk * knw[h * DH + j];
        const float x2 = rowp[QD + h * DH + 64 + j] * rk * knw[h * DH + 64 + j];
        kb[((long)h * S_LEN + s) * DH + j]      = f2bf(x1 * cs - x2 * sn);
        kb[((long)h * S_LEN + s) * DH + 64 + j] = f2bf(x2 * cs + x1 * sn);
    }
    // V -> tiled-transposed: vt2[kh][s/32][d][s%32]
    for (int u = tid; u < KD; u += 256) {
        const int hh = u >> 7, d = u & 127;
        vt2[(((long)hh * (S_LEN / 32) + (s >> 5)) * DH + d) * 32 + (s & 31)] =
            f2bf(rowp[QD + KD + u]);
    }
}

// ---------------- flash attention: 8 waves / block, one KV group / block ----------------
__global__ __launch_bounds__(512) void attn_fwd(
    const unsigned short* __restrict__ qb,   // [NH][S][DH]
    const unsigned short* __restrict__ kb,   // [NKH][S][DH] (pre-scaled)
    const unsigned short* __restrict__ vt2,  // [NKH][S/32][DH][32]
    unsigned short* __restrict__ attnb)      // [S][QD]
{
    __shared__ __align__(16) unsigned char sK[2][8192];  // [32 s][16 ch 16B], ch ^ (row&15)
    __shared__ __align__(16) unsigned char sV[2][8192];  // [128 d][4 ch 16B], ch ^ ((row>>1)&3)

    const int qt   = 63 - blockIdx.x;        // big q-tiles dispatched first
    const int kh   = blockIdx.y;
    const int tid  = threadIdx.x;
    const int w    = tid >> 6;
    const int lane = tid & 63;
    const int lq   = lane & 31;
    const int hi   = lane >> 5;
    const int hi8  = hi * 8;
    const int hi4  = hi * 4;
    const int q0   = qt * 32;
    const int NT   = qt + 1;

    const unsigned char* kgb = (const unsigned char*)(kb + (long)kh * S_LEN * DH);
    const unsigned char* vgb = (const unsigned char*)vt2 + (long)kh * (S_LEN / 32) * 8192;

    // staging: threads 0-255 stage K (2x16B), threads 256-511 stage V (2x16B)
    const int ksrc_off = (((tid & 15) ^ (tid >> 4)) & 15) << 4;
    const int u        = tid & 255;
    const int vsrc_off = ((u & 3) ^ ((u >> 3) & 3)) << 4;

    const float RTHR = 8.0f;   // defer-max threshold (scale already folded into K)

    // Q fragments (B-operand): Q[q0+lq][c*16 + hi*8 + e]
    bf16x8 qf[8];
    if (w < 7) {
        const int h = kh * NG + w;
        const unsigned short* qrow = qb + ((long)h * S_LEN + q0 + lq) * DH;
        #pragma unroll
        for (int c = 0; c < 8; ++c)
            qf[c] = *(const bf16x8*)(qrow + c * 16 + hi8);
    }

    f32x16 o[4] = {};
    float m = -3e38f;
    float l = 0.f;

    // prologue: stage tile 0 into buf 0
    if (tid < 256) {
        #pragma unroll
        for (int j = 0; j < 2; ++j)
            __builtin_amdgcn_global_load_lds(AS1(kgb + ((tid >> 4) + 16 * j) * 256 + ksrc_off),
                                             AS3(&sK[0][0] + w * 1024 + j * 4096), 16, 0, 0);
    } else {
        #pragma unroll
        for (int j = 0; j < 2; ++j)
            __builtin_amdgcn_global_load_lds(AS1(vgb + ((u >> 2) + 64 * j) * 64 + vsrc_off),
                                             AS3(&sV[0][0] + (w - 4) * 1024 + j * 4096), 16, 0, 0);
    }

    for (int t = 0; t < NT; ++t) {
        __syncthreads();   // drains vmcnt: buf[t&1] ready

        if (t + 1 < NT) {
            const int b = (t + 1) & 1;
            if (tid < 256) {
                const unsigned char* ks = kgb + (long)(t + 1) * 8192;
                #pragma unroll
                for (int j = 0; j < 2; ++j)
                    __builtin_amdgcn_global_load_lds(AS1(ks + ((tid >> 4) + 16 * j) * 256 + ksrc_off),
                                                     AS3(&sK[b][0] + w * 1024 + j * 4096), 16, 0, 0);
            } else {
                const unsigned char* vs = vgb + (long)(t + 1) * 8192;
                #pragma unroll
                for (int j = 0; j < 2; ++j)
                    __builtin_amdgcn_global_load_lds(AS1(vs + ((u >> 2) + 64 * j) * 64 + vsrc_off),
                                                     AS3(&sV[b][0] + (w - 4) * 1024 + j * 4096), 16, 0, 0);
            }
        }

        if (w < 7) {
            const unsigned char* sKb = sK[t & 1];
            const unsigned char* sVb = sV[t & 1];

            // ---- QK^T (swapped): sc[col=q][reg-row=k] ----
            bf16x8 kf[8];
            #pragma unroll
            for (int c = 0; c < 8; ++c)
                kf[c] = *(const bf16x8*)(sKb + lq * 256 + (((2 * c + hi) ^ (lq & 15)) << 4));
            f32x16 sc = {};
            #pragma unroll
            for (int c = 0; c < 8; ++c)
                sc = __builtin_amdgcn_mfma_f32_32x32x16_bf16(kf[c], qf[c], sc, 0, 0, 0);

            // ---- mask (diagonal tile only) ----
            float s[16];
            if (t == NT - 1) {
                #pragma unroll
                for (int r = 0; r < 16; ++r) {
                    const int kr = (r & 3) + 8 * (r >> 2) + hi4;
                    s[r] = (kr > lq) ? -3e38f : sc[r];
                }
            } else {
                #pragma unroll
                for (int r = 0; r < 16; ++r) s[r] = sc[r];
            }

            // ---- online softmax, lane-local ----
            float mx = s[0];
            #pragma unroll
            for (int r = 1; r < 16; ++r) mx = fmaxf(mx, s[r]);
            mx = fmaxf(mx, __shfl_xor(mx, 32));

            if (!__all(mx <= m + RTHR)) {
                const float nm  = fmaxf(m, mx);
                const float fac = __expf(m - nm);
                l *= fac;
                #pragma unroll
                for (int d0 = 0; d0 < 4; ++d0)
                    #pragma unroll
                    for (int r = 0; r < 16; ++r) o[d0][r] *= fac;
                m = nm;
            }

            float p[16];
            float ps = 0.f;
            #pragma unroll
            for (int r = 0; r < 16; ++r) {
                p[r] = __expf(s[r] - m);
                ps += p[r];
            }
            ps += __shfl_xor(ps, 32);
            l += ps;

            // ---- P -> PV B-fragments: cvt_pk pack + half-swap ----
            unsigned pa01 = cvtpk(p[0],  p[1]),  pa23 = cvtpk(p[2],  p[3]);
            unsigned pb01 = cvtpk(p[4],  p[5]),  pb23 = cvtpk(p[6],  p[7]);
            unsigned pc01 = cvtpk(p[8],  p[9]),  pc23 = cvtpk(p[10], p[11]);
            unsigned pd01 = cvtpk(p[12], p[13]), pd23 = cvtpk(p[14], p[15]);
            unsigned xa01 = __shfl_xor((int)pa01, 32), xa23 = __shfl_xor((int)pa23, 32);
            unsigned xb01 = __shfl_xor((int)pb01, 32), xb23 = __shfl_xor((int)pb23, 32);
            unsigned xc01 = __shfl_xor((int)pc01, 32), xc23 = __shfl_xor((int)pc23, 32);
            unsigned xd01 = __shfl_xor((int)pd01, 32), xd23 = __shfl_xor((int)pd23, 32);

            union { unsigned uu[4]; bf16x8 v; } pf0, pf1;
            pf0.uu[0] = hi ? xb01 : pa01;
            pf0.uu[1] = hi ? xb23 : pa23;
            pf0.uu[2] = hi ? pb01 : xa01;
            pf0.uu[3] = hi ? pb23 : xa23;
            pf1.uu[0] = hi ? xd01 : pc01;
            pf1.uu[1] = hi ? xd23 : pc23;
            pf1.uu[2] = hi ? pd01 : xc01;
            pf1.uu[3] = hi ? pd23 : xc23;

            // ---- PV (swapped): o[col=q][reg-row=d], V from LDS ----
            #pragma unroll
            for (int d0 = 0; d0 < 4; ++d0) {
                const int row = d0 * 32 + lq;
                const int sw  = (lq >> 1) & 3;
                bf16x8 vf0 = *(const bf16x8*)(sVb + row * 64 + ((hi ^ sw) << 4));
                bf16x8 vf1 = *(const bf16x8*)(sVb + row * 64 + (((2 + hi) ^ sw) << 4));
                o[d0] = __builtin_amdgcn_mfma_f32_32x32x16_bf16(vf0, pf0.v, o[d0], 0, 0, 0);
                o[d0] = __builtin_amdgcn_mfma_f32_32x32x16_bf16(vf1, pf1.v, o[d0], 0, 0, 0);
            }
        }
    }

    if (w == 7) return;

    // ---- epilogue: out[q0+lq][h*DH + d], d = d0*32 + 8g + hi4 + 0..3 ----
    const float rl = 1.0f / l;
    unsigned short* orow = attnb + (long)(q0 + lq) * QD + (kh * NG + w) * DH;
    #pragma unroll
    for (int d0 = 0; d0 < 4; ++d0) {
        #pragma unroll
        for (int g = 0; g < 4; ++g) {
            ushort4 s4;
            s4.x = f2bf(o[d0][4 * g + 0] * rl);
            s4.y = f2bf(o[d0][4 * g + 1] * rl);
            s4.z = f2bf(o[d0][4 * g + 2] * rl);
            s4.w = f2bf(o[d0][4 * g + 3] * rl);
            *(ushort4*)(orow + d0 * 32 + 8 * g + hi4) = s4;
        }
    }
}

// ---------------- launch ----------------
extern "C" void kernel_launch(void* const* d_in, const int* in_sizes, int n_in,
                              void* d_out, int out_size, void* d_ws, size_t ws_size,
                              hipStream_t stream) {
    const int*   positions = (const int*)d_in[0];
    const float* hidden    = (const float*)d_in[1];
    const float* qkv_w     = (const float*)d_in[2];
    const float* qkv_b     = (const float*)d_in[3];
    const float* qnw       = (const float*)d_in[4];
    const float* knw       = (const float*)d_in[5];
    const float* o_w       = (const float*)d_in[6];
    float* out = (float*)d_out;

    unsigned char* ws = (unsigned char*)d_ws;
    unsigned short* hb    = (unsigned short*)(ws);               // 14,680,064 B
    unsigned short* w1    = (unsigned short*)(ws + 14680064);    // 33,030,144 B
    float*          qkvf  = (float*)(ws + 47710208);             // 37,748,736 B
    unsigned short* qbuf  = (unsigned short*)(ws + 85458944);    // 14,680,064 B
    unsigned short* kbuf  = (unsigned short*)(ws + 100139008);   //  2,097,152 B
    unsigned short* vtb   = (unsigned short*)(ws + 102236160);   //  2,097,152 B
    unsigned short* attnb = (unsigned short*)(ws);               // reuse hb (dead after GEMM1)
    unsigned short* w2    = (unsigned short*)(ws + 14680064);    // reuse w1 (dead after GEMM1)

    const int na4 = S_LEN * HIDDEN / 4;
    const int nb4 = NQKV * HIDDEN / 4;
    cvt2_f32_bf16<<<(na4 + nb4 + 255) / 256, 256, 0, stream>>>(hidden, hb, na4, qkv_w, w1, nb4);
    gemm_bf16<<<(NQKV / 128) * (S_LEN / 128), 256, 0, stream>>>(hb, w1, qkvf, qkv_b,
                                                                S_LEN, NQKV, HIDDEN, S_LEN / 128);
    qkv_post<<<S_LEN, 256, 0, stream>>>(qkvf, positions, qnw, knw, qbuf, kbuf, vtb);
    attn_fwd<<<dim3(S_LEN / 32, NKH), 512, 0, stream>>>(qbuf, kbuf, vtb, attnb);
    cvt_f32_bf16<<<(HIDDEN * QD / 4 + 255) / 256, 256, 0, stream>>>(o_w, w2, HIDDEN * QD / 4);
    gemm_bf16<<<(HIDDEN / 128) * (S_LEN / 128), 256, 0, stream>>>(attnb, w2, out, nullptr,
                                                                  S_LEN, HIDDEN, QD, S_LEN / 128);
}

// Round 10
// 281.689 us; speedup vs baseline: 1.5694x; 1.0313x over previous
//
#include <hip/hip_runtime.h>
#include <hip/hip_bf16.h>
#include <stdint.h>

#define S_LEN 2048
#define HIDDEN 3584
#define NH 28
#define NKH 4
#define DH 128
#define NG 7          // NH / NKH
#define NQKV 4608     // (NH + 2*NKH) * DH
#define QD 3584       // NH*DH
#define KD 512        // NKH*DH

using bf16x8 = __attribute__((ext_vector_type(8))) __bf16;
using f32x4  = __attribute__((ext_vector_type(4))) float;
using f32x16 = __attribute__((ext_vector_type(16))) float;

#define AS3(p) ((__attribute__((address_space(3))) void*)(p))
#define AS1(p) ((const __attribute__((address_space(1))) void*)(p))

__device__ __forceinline__ unsigned short f2bf(float f) {
    unsigned u = __float_as_uint(f);
    u += 0x7FFFu + ((u >> 16) & 1u);
    return (unsigned short)(u >> 16);
}
__device__ __forceinline__ unsigned cvtpk(float a, float b) {
    unsigned r;
    asm("v_cvt_pk_bf16_f32 %0, %1, %2" : "=v"(r) : "v"(a), "v"(b));
    return r;
}

// ---------------- f32 -> bf16 convert (two tensors fused) ----------------
__global__ void cvt2_f32_bf16(const float* __restrict__ a, unsigned short* __restrict__ oa, int na4,
                              const float* __restrict__ b, unsigned short* __restrict__ ob, int nb4) {
    int i = blockIdx.x * blockDim.x + threadIdx.x;
    const float* src;
    unsigned short* dst;
    int n;
    if (i < na4)            { src = a; dst = oa; n = i; }
    else if (i < na4 + nb4) { src = b; dst = ob; n = i - na4; }
    else return;
    float4 v = ((const float4*)src)[n];
    ushort4 o;
    o.x = f2bf(v.x); o.y = f2bf(v.y); o.z = f2bf(v.z); o.w = f2bf(v.w);
    ((ushort4*)dst)[n] = o;
}

__global__ void cvt_f32_bf16(const float* __restrict__ in,
                             unsigned short* __restrict__ out, int n4) {
    int i = blockIdx.x * blockDim.x + threadIdx.x;
    if (i >= n4) return;
    float4 v = ((const float4*)in)[i];
    ushort4 o;
    o.x = f2bf(v.x); o.y = f2bf(v.y); o.z = f2bf(v.z); o.w = f2bf(v.w);
    ((ushort4*)out)[i] = o;
}

// ---------------- big-tile bf16 GEMM: C[M][N] = A[M][K]*B[N][K]^T (+bias) ----------------
// 256 x BN tile (BN=192 or 128), BK=64, 8 waves (2M x 4N), per-wave 128 x BN/4.
// Double-buffered static LDS. Per K-tile: {ds_read all frags + MFMA(mi0-3)} barrier
// {stage kt+2 into just-read buf + MFMA(mi4-7)} vmcnt(SPW) barrier — counted vmcnt keeps
// the prefetch in flight across barriers (T4); intensity M*N/(M+N) sets the ceiling.
template<int BN>
__global__ __launch_bounds__(512, 2) void gemm_big(
    const unsigned short* __restrict__ A,
    const unsigned short* __restrict__ B,
    float* __restrict__ C,
    const float* __restrict__ bias,
    int M, int N, int K)
{
    constexpr int NF    = BN / 64;        // N-frags per wave (3 or 2)
    constexpr int WN    = BN / 4;         // cols per wave (48 or 32)
    constexpr int BBLK  = BN / 8;         // B-tile 1KB blocks (24 or 16)
    constexpr int SBLK  = 32 + BBLK;      // total 1KB blocks per K-tile (56 or 48)
    constexpr int SPW   = SBLK / 8;       // gload_lds per thread per K-tile (7 or 6)
    constexpr int TILEB = SBLK * 1024;    // LDS bytes per buffer

    __shared__ __align__(16) unsigned char dsmem[2 * TILEB];

    const int tid  = threadIdx.x;
    const int w    = tid >> 6;
    const int lane = tid & 63;
    const int lr   = lane & 15;
    const int lg   = lane >> 4;
    const int wr   = w >> 2;              // 0-1: M half
    const int wc   = w & 3;               // 0-3: N quarter
    const int m0   = blockIdx.y * 256;
    const int n0   = blockIdx.x * BN;
    const long K2  = (long)K * 2;

    const int srow = lane >> 3;                         // 0-7
    const int scw  = 16 * ((lane & 7) ^ srow);          // pre-swizzled source chunk byte
    const unsigned char* Ab = (const unsigned char*)A;
    const unsigned char* Bb = (const unsigned char*)B;

    // stage K-tile kt into buf: blocks w*SPW..w*SPW+SPW-1; A blocks 0-31, B blocks 32+
    auto stage = [&](int kt, unsigned char* buf) {
        const long kb = (long)kt * 128;
        #pragma unroll
        for (int j = 0; j < SPW; ++j) {
            const int blk = w * SPW + j;
            const unsigned char* src = (blk < 32)
                ? Ab + (long)(m0 + blk * 8 + srow) * K2 + kb + scw
                : Bb + (long)(n0 + (blk - 32) * 8 + srow) * K2 + kb + scw;
            __builtin_amdgcn_global_load_lds(AS1(src), AS3(buf + blk * 1024), 16, 0, 0);
        }
    };

    f32x4 acc[8][NF] = {};

    stage(0, dsmem);
    stage(1, dsmem + TILEB);
    if constexpr (SPW == 7) asm volatile("s_waitcnt vmcnt(7)" ::: "memory");
    else                    asm volatile("s_waitcnt vmcnt(6)" ::: "memory");
    __builtin_amdgcn_s_barrier();

    const int nk = K >> 6;
    for (int kt = 0; kt < nk; ++kt) {
        unsigned char* buf = dsmem + (kt & 1) * TILEB;
        const unsigned char* As = buf;
        const unsigned char* Bs = buf + 32768;

        // ---- region 1: all frag reads + first-half MFMA ----
        bf16x8 a[8][2], bfr[NF][2];
        #pragma unroll
        for (int mi = 0; mi < 8; ++mi) {
            const int row = wr * 128 + mi * 16 + lr;
            #pragma unroll
            for (int kk = 0; kk < 2; ++kk)
                a[mi][kk] = *(const bf16x8*)(As + row * 128 +
                                             ((kk * 64 + lg * 16) ^ ((lr & 7) << 4)));
        }
        #pragma unroll
        for (int ni = 0; ni < NF; ++ni) {
            const int row = wc * WN + ni * 16 + lr;
            #pragma unroll
            for (int kk = 0; kk < 2; ++kk)
                bfr[ni][kk] = *(const bf16x8*)(Bs + row * 128 +
                                               ((kk * 64 + lg * 16) ^ ((lr & 7) << 4)));
        }

        __builtin_amdgcn_s_setprio(1);
        #pragma unroll
        for (int mi = 0; mi < 4; ++mi)
            #pragma unroll
            for (int ni = 0; ni < NF; ++ni)
                #pragma unroll
                for (int kk = 0; kk < 2; ++kk)
                    acc[mi][ni] = __builtin_amdgcn_mfma_f32_16x16x32_bf16(
                        a[mi][kk], bfr[ni][kk], acc[mi][ni], 0, 0, 0);
        __builtin_amdgcn_s_setprio(0);

        asm volatile("s_waitcnt lgkmcnt(0)" ::: "memory");   // all LDS reads retired
        __builtin_amdgcn_s_barrier();                        // buf now safe to overwrite

        // ---- region 2: prefetch kt+2 into buf + second-half MFMA ----
        if (kt + 2 < nk) stage(kt + 2, buf);

        __builtin_amdgcn_s_setprio(1);
        #pragma unroll
        for (int mi = 4; mi < 8; ++mi)
            #pragma unroll
            for (int ni = 0; ni < NF; ++ni)
                #pragma unroll
                for (int kk = 0; kk < 2; ++kk)
                    acc[mi][ni] = __builtin_amdgcn_mfma_f32_16x16x32_bf16(
                        a[mi][kk], bfr[ni][kk], acc[mi][ni], 0, 0, 0);
        __builtin_amdgcn_s_setprio(0);

        if (kt + 2 < nk) {
            if constexpr (SPW == 7) asm volatile("s_waitcnt vmcnt(7)" ::: "memory");
            else                    asm volatile("s_waitcnt vmcnt(6)" ::: "memory");
        } else {
            asm volatile("s_waitcnt vmcnt(0)" ::: "memory");
        }
        __builtin_amdgcn_s_barrier();                        // next buffer fully landed
    }

    // ---- epilogue ----
    #pragma unroll
    for (int mi = 0; mi < 8; ++mi) {
        #pragma unroll
        for (int ni = 0; ni < NF; ++ni) {
            const int col = n0 + wc * WN + ni * 16 + lr;
            const float bv = bias ? bias[col] : 0.0f;
            #pragma unroll
            for (int j = 0; j < 4; ++j) {
                const int row = m0 + wr * 128 + mi * 16 + lg * 4 + j;
                C[(long)row * N + col] = acc[mi][ni][j] + bv;
            }
        }
    }
}

// ---------------- QKV post: RMSNorm(q,k) + RoPE, layout shuffle ----------------
__global__ __launch_bounds__(256) void qkv_post(
    const float* __restrict__ qkv,       // [S][NQKV]
    const int* __restrict__ positions,
    const float* __restrict__ qnw,       // [QD]
    const float* __restrict__ knw,       // [KD]
    unsigned short* __restrict__ qb,     // [NH][S][DH]
    unsigned short* __restrict__ kb,     // [NKH][S][DH]
    unsigned short* __restrict__ vt2)    // [NKH][S/32][DH][32]
{
    const int s   = blockIdx.x;
    const int tid = threadIdx.x;
    const float* rowp = qkv + (long)s * NQKV;
    __shared__ float red[256];
    __shared__ float s_rq, s_rk;

    float aq = 0.f;
    for (int i = tid; i < QD; i += 256) { float v = rowp[i]; aq += v * v; }
    red[tid] = aq; __syncthreads();
    for (int off = 128; off > 0; off >>= 1) {
        if (tid < off) red[tid] += red[tid + off];
        __syncthreads();
    }
    if (tid == 0) s_rq = rsqrtf(red[0] / (float)QD + 1e-6f);
    __syncthreads();

    float ak = 0.f;
    for (int i = tid; i < KD; i += 256) { float v = rowp[QD + i]; ak += v * v; }
    red[tid] = ak; __syncthreads();
    for (int off = 128; off > 0; off >>= 1) {
        if (tid < off) red[tid] += red[tid + off];
        __syncthreads();
    }
    if (tid == 0) s_rk = rsqrtf(red[0] / (float)KD + 1e-6f);
    __syncthreads();

    const float rq  = s_rq, rk = s_rk * 0.08838834764831845f;  // fold softmax scale into K
    const float pos = (float)positions[s];
    const float c_lnf = 0.21586735253866598f; // ln(1e6)/64

    for (int u = tid; u < NH * 64; u += 256) {
        const int h = u >> 6, j = u & 63;
        const float inv = expf(-(float)j * c_lnf);
        float sn, cs;
        sincosf(pos * inv, &sn, &cs);
        const float x1 = rowp[h * DH + j]      * rq * qnw[h * DH + j];
        const float x2 = rowp[h * DH + 64 + j] * rq * qnw[h * DH + 64 + j];
        qb[((long)h * S_LEN + s) * DH + j]      = f2bf(x1 * cs - x2 * sn);
        qb[((long)h * S_LEN + s) * DH + 64 + j] = f2bf(x2 * cs + x1 * sn);
    }
    for (int u = tid; u < NKH * 64; u += 256) {
        const int h = u >> 6, j = u & 63;
        const float inv = expf(-(float)j * c_lnf);
        float sn, cs;
        sincosf(pos * inv, &sn, &cs);
        const float x1 = rowp[QD + h * DH + j]      * rk * knw[h * DH + j];
        const float x2 = rowp[QD + h * DH + 64 + j] * rk * knw[h * DH + 64 + j];
        kb[((long)h * S_LEN + s) * DH + j]      = f2bf(x1 * cs - x2 * sn);
        kb[((long)h * S_LEN + s) * DH + 64 + j] = f2bf(x2 * cs + x1 * sn);
    }
    // V -> tiled-transposed: vt2[kh][s/32][d][s%32]
    for (int u = tid; u < KD; u += 256) {
        const int hh = u >> 7, d = u & 127;
        vt2[(((long)hh * (S_LEN / 32) + (s >> 5)) * DH + d) * 32 + (s & 31)] =
            f2bf(rowp[QD + KD + u]);
    }
}

// ---------------- flash attention: 8 waves / block, one KV group / block ----------------
__global__ __launch_bounds__(512) void attn_fwd(
    const unsigned short* __restrict__ qb,   // [NH][S][DH]
    const unsigned short* __restrict__ kb,   // [NKH][S][DH] (pre-scaled)
    const unsigned short* __restrict__ vt2,  // [NKH][S/32][DH][32]
    unsigned short* __restrict__ attnb)      // [S][QD]
{
    __shared__ __align__(16) unsigned char sK[2][8192];  // [32 s][16 ch 16B], ch ^ (row&15)
    __shared__ __align__(16) unsigned char sV[2][8192];  // [128 d][4 ch 16B], ch ^ ((row>>1)&3)

    const int qt   = 63 - blockIdx.x;        // big q-tiles dispatched first
    const int kh   = blockIdx.y;
    const int tid  = threadIdx.x;
    const int w    = tid >> 6;
    const int lane = tid & 63;
    const int lq   = lane & 31;
    const int hi   = lane >> 5;
    const int hi8  = hi * 8;
    const int hi4  = hi * 4;
    const int q0   = qt * 32;
    const int NT   = qt + 1;

    const unsigned char* kgb = (const unsigned char*)(kb + (long)kh * S_LEN * DH);
    const unsigned char* vgb = (const unsigned char*)vt2 + (long)kh * (S_LEN / 32) * 8192;

    // staging: threads 0-255 stage K (2x16B), threads 256-511 stage V (2x16B)
    const int ksrc_off = (((tid & 15) ^ (tid >> 4)) & 15) << 4;
    const int u        = tid & 255;
    const int vsrc_off = ((u & 3) ^ ((u >> 3) & 3)) << 4;

    const float RTHR = 8.0f;   // defer-max threshold (scale already folded into K)

    bf16x8 qf[8];
    if (w < 7) {
        const int h = kh * NG + w;
        const unsigned short* qrow = qb + ((long)h * S_LEN + q0 + lq) * DH;
        #pragma unroll
        for (int c = 0; c < 8; ++c)
            qf[c] = *(const bf16x8*)(qrow + c * 16 + hi8);
    }

    f32x16 o[4] = {};
    float m = -3e38f;
    float l = 0.f;

    if (tid < 256) {
        #pragma unroll
        for (int j = 0; j < 2; ++j)
            __builtin_amdgcn_global_load_lds(AS1(kgb + ((tid >> 4) + 16 * j) * 256 + ksrc_off),
                                             AS3(&sK[0][0] + w * 1024 + j * 4096), 16, 0, 0);
    } else {
        #pragma unroll
        for (int j = 0; j < 2; ++j)
            __builtin_amdgcn_global_load_lds(AS1(vgb + ((u >> 2) + 64 * j) * 64 + vsrc_off),
                                             AS3(&sV[0][0] + (w - 4) * 1024 + j * 4096), 16, 0, 0);
    }

    for (int t = 0; t < NT; ++t) {
        __syncthreads();   // drains vmcnt: buf[t&1] ready

        if (t + 1 < NT) {
            const int b = (t + 1) & 1;
            if (tid < 256) {
                const unsigned char* ks = kgb + (long)(t + 1) * 8192;
                #pragma unroll
                for (int j = 0; j < 2; ++j)
                    __builtin_amdgcn_global_load_lds(AS1(ks + ((tid >> 4) + 16 * j) * 256 + ksrc_off),
                                                     AS3(&sK[b][0] + w * 1024 + j * 4096), 16, 0, 0);
            } else {
                const unsigned char* vs = vgb + (long)(t + 1) * 8192;
                #pragma unroll
                for (int j = 0; j < 2; ++j)
                    __builtin_amdgcn_global_load_lds(AS1(vs + ((u >> 2) + 64 * j) * 64 + vsrc_off),
                                                     AS3(&sV[b][0] + (w - 4) * 1024 + j * 4096), 16, 0, 0);
            }
        }

        if (w < 7) {
            const unsigned char* sKb = sK[t & 1];
            const unsigned char* sVb = sV[t & 1];

            bf16x8 kf[8];
            #pragma unroll
            for (int c = 0; c < 8; ++c)
                kf[c] = *(const bf16x8*)(sKb + lq * 256 + (((2 * c + hi) ^ (lq & 15)) << 4));
            f32x16 sc = {};
            #pragma unroll
            for (int c = 0; c < 8; ++c)
                sc = __builtin_amdgcn_mfma_f32_32x32x16_bf16(kf[c], qf[c], sc, 0, 0, 0);

            float s[16];
            if (t == NT - 1) {
                #pragma unroll
                for (int r = 0; r < 16; ++r) {
                    const int kr = (r & 3) + 8 * (r >> 2) + hi4;
                    s[r] = (kr > lq) ? -3e38f : sc[r];
                }
            } else {
                #pragma unroll
                for (int r = 0; r < 16; ++r) s[r] = sc[r];
            }

            float mx = s[0];
            #pragma unroll
            for (int r = 1; r < 16; ++r) mx = fmaxf(mx, s[r]);
            mx = fmaxf(mx, __shfl_xor(mx, 32));

            if (!__all(mx <= m + RTHR)) {
                const float nm  = fmaxf(m, mx);
                const float fac = __expf(m - nm);
                l *= fac;
                #pragma unroll
                for (int d0 = 0; d0 < 4; ++d0)
                    #pragma unroll
                    for (int r = 0; r < 16; ++r) o[d0][r] *= fac;
                m = nm;
            }

            float p[16];
            float ps = 0.f;
            #pragma unroll
            for (int r = 0; r < 16; ++r) {
                p[r] = __expf(s[r] - m);
                ps += p[r];
            }
            ps += __shfl_xor(ps, 32);
            l += ps;

            unsigned pa01 = cvtpk(p[0],  p[1]),  pa23 = cvtpk(p[2],  p[3]);
            unsigned pb01 = cvtpk(p[4],  p[5]),  pb23 = cvtpk(p[6],  p[7]);
            unsigned pc01 = cvtpk(p[8],  p[9]),  pc23 = cvtpk(p[10], p[11]);
            unsigned pd01 = cvtpk(p[12], p[13]), pd23 = cvtpk(p[14], p[15]);
            unsigned xa01 = __shfl_xor((int)pa01, 32), xa23 = __shfl_xor((int)pa23, 32);
            unsigned xb01 = __shfl_xor((int)pb01, 32), xb23 = __shfl_xor((int)pb23, 32);
            unsigned xc01 = __shfl_xor((int)pc01, 32), xc23 = __shfl_xor((int)pc23, 32);
            unsigned xd01 = __shfl_xor((int)pd01, 32), xd23 = __shfl_xor((int)pd23, 32);

            union { unsigned uu[4]; bf16x8 v; } pf0, pf1;
            pf0.uu[0] = hi ? xb01 : pa01;
            pf0.uu[1] = hi ? xb23 : pa23;
            pf0.uu[2] = hi ? pb01 : xa01;
            pf0.uu[3] = hi ? pb23 : xa23;
            pf1.uu[0] = hi ? xd01 : pc01;
            pf1.uu[1] = hi ? xd23 : pc23;
            pf1.uu[2] = hi ? pd01 : xc01;
            pf1.uu[3] = hi ? pd23 : xc23;

            #pragma unroll
            for (int d0 = 0; d0 < 4; ++d0) {
                const int row = d0 * 32 + lq;
                const int sw  = (lq >> 1) & 3;
                bf16x8 vf0 = *(const bf16x8*)(sVb + row * 64 + ((hi ^ sw) << 4));
                bf16x8 vf1 = *(const bf16x8*)(sVb + row * 64 + (((2 + hi) ^ sw) << 4));
                o[d0] = __builtin_amdgcn_mfma_f32_32x32x16_bf16(vf0, pf0.v, o[d0], 0, 0, 0);
                o[d0] = __builtin_amdgcn_mfma_f32_32x32x16_bf16(vf1, pf1.v, o[d0], 0, 0, 0);
            }
        }
    }

    if (w == 7) return;

    const float rl = 1.0f / l;
    unsigned short* orow = attnb + (long)(q0 + lq) * QD + (kh * NG + w) * DH;
    #pragma unroll
    for (int d0 = 0; d0 < 4; ++d0) {
        #pragma unroll
        for (int g = 0; g < 4; ++g) {
            ushort4 s4;
            s4.x = f2bf(o[d0][4 * g + 0] * rl);
            s4.y = f2bf(o[d0][4 * g + 1] * rl);
            s4.z = f2bf(o[d0][4 * g + 2] * rl);
            s4.w = f2bf(o[d0][4 * g + 3] * rl);
            *(ushort4*)(orow + d0 * 32 + 8 * g + hi4) = s4;
        }
    }
}

// ---------------- launch ----------------
extern "C" void kernel_launch(void* const* d_in, const int* in_sizes, int n_in,
                              void* d_out, int out_size, void* d_ws, size_t ws_size,
                              hipStream_t stream) {
    const int*   positions = (const int*)d_in[0];
    const float* hidden    = (const float*)d_in[1];
    const float* qkv_w     = (const float*)d_in[2];
    const float* qkv_b     = (const float*)d_in[3];
    const float* qnw       = (const float*)d_in[4];
    const float* knw       = (const float*)d_in[5];
    const float* o_w       = (const float*)d_in[6];
    float* out = (float*)d_out;

    unsigned char* ws = (unsigned char*)d_ws;
    unsigned short* hb    = (unsigned short*)(ws);               // 14,680,064 B
    unsigned short* w1    = (unsigned short*)(ws + 14680064);    // 33,030,144 B
    float*          qkvf  = (float*)(ws + 47710208);             // 37,748,736 B
    unsigned short* qbuf  = (unsigned short*)(ws + 85458944);    // 14,680,064 B
    unsigned short* kbuf  = (unsigned short*)(ws + 100139008);   //  2,097,152 B
    unsigned short* vtb   = (unsigned short*)(ws + 102236160);   //  2,097,152 B
    unsigned short* attnb = (unsigned short*)(ws);               // reuse hb (dead after GEMM1)
    unsigned short* w2    = (unsigned short*)(ws + 14680064);    // reuse w1 (dead after GEMM1)

    const int na4 = S_LEN * HIDDEN / 4;
    const int nb4 = NQKV * HIDDEN / 4;
    cvt2_f32_bf16<<<(na4 + nb4 + 255) / 256, 256, 0, stream>>>(hidden, hb, na4, qkv_w, w1, nb4);
    gemm_big<192><<<dim3(NQKV / 192, S_LEN / 256), 512, 0, stream>>>(
        hb, w1, qkvf, qkv_b, S_LEN, NQKV, HIDDEN);
    qkv_post<<<S_LEN, 256, 0, stream>>>(qkvf, positions, qnw, knw, qbuf, kbuf, vtb);
    attn_fwd<<<dim3(S_LEN / 32, NKH), 512, 0, stream>>>(qbuf, kbuf, vtb, attnb);
    cvt_f32_bf16<<<(HIDDEN * QD / 4 + 255) / 256, 256, 0, stream>>>(o_w, w2, HIDDEN * QD / 4);
    gemm_big<128><<<dim3(HIDDEN / 128, S_LEN / 256), 512, 0, stream>>>(
        attnb, w2, out, nullptr, S_LEN, HIDDEN, QD);
}